// Round 1
// baseline (379.546 us; speedup 1.0000x reference)
//
#include <hip/hip_runtime.h>
#include <math.h>

// Problem constants (from setup_inputs): B=64, L=128, H=16, O=8
#define LQ   128
#define BQ   64
#define LL   (LQ*LQ)
#define H1   16
#define O2   8
#define TILE 16
#define REG  18          // TILE + 2 halo
#define NPTS (REG*REG)   // 324

__device__ __forceinline__ int wrapi(int v) { return v & (LQ - 1); }

// Workspace layout (floats):
//   [0]                     xaxis_r  (B*L = 8192)
//   [8192]                  xaxis_i  (8192)
//   [16384]                 seed_r   (B*L*L)
//   [16384 + 1*B*LL]        seed_i
//   [16384 + 2*B*LL]        pc
//   [16384 + 3*B*LL]        pavg
// total = 16384 + 4*1048576 floats = ~16.8 MB
#define WS_SEED_R 16384
#define WS_BLL    ((size_t)BQ * LL)

// ---------------------------------------------------------------------------
// Kernel 1: x-axis Wilson line: xaxis[b,i] = prod_{t<i} (x0 + i*x1)[b,t,0]
__global__ void k_xaxis(const float* __restrict__ x, float* __restrict__ ws) {
    int b = threadIdx.x;
    if (b >= BQ) return;
    float* xr = ws;
    float* xi = ws + BQ * LQ;
    const float* uxr = x + (size_t)(b * 4 + 0) * LL;
    const float* uxi = x + (size_t)(b * 4 + 1) * LL;
    float cr = 1.f, ci = 0.f;
    xr[b * LQ] = cr; xi[b * LQ] = ci;
    for (int t = 0; t < LQ - 1; ++t) {
        float ur = uxr[t * LQ];   // column j = 0
        float ui = uxi[t * LQ];
        float nr = cr * ur - ci * ui;
        float ni = cr * ui + ci * ur;
        cr = nr; ci = ni;
        xr[b * LQ + t + 1] = cr;
        xi[b * LQ + t + 1] = ci;
    }
}

// ---------------------------------------------------------------------------
// Kernel 2: seed[b,i,j] = conj( xaxis[b,i] * prod_{t<j} (x2 + i*x3)[b,i,t] )
__global__ void k_seed(const float* __restrict__ x, float* __restrict__ ws) {
    int t = blockIdx.x * blockDim.x + threadIdx.x;
    if (t >= BQ * LQ) return;
    int b = t >> 7;          // / LQ
    int i = t & (LQ - 1);
    const float* xr = ws;
    const float* xi = ws + BQ * LQ;
    float cr = xr[t], ci = xi[t];
    float* sr = ws + WS_SEED_R;
    float* si = sr + WS_BLL;
    const float* uyr = x + (size_t)(b * 4 + 2) * LL + (size_t)i * LQ;
    const float* uyi = x + (size_t)(b * 4 + 3) * LL + (size_t)i * LQ;
    size_t base = (size_t)b * LL + (size_t)i * LQ;
    sr[base] = cr; si[base] = -ci;
    for (int j = 0; j < LQ - 1; ++j) {
        float ur = uyr[j], ui = uyi[j];
        float nr = cr * ur - ci * ui;
        float ni = cr * ui + ci * ur;
        cr = nr; ci = ni;
        sr[base + j + 1] = cr;
        si[base + j + 1] = -ci;
    }
}

// ---------------------------------------------------------------------------
// Kernel 3: pc = cos(ax(i,j) + ay(i+1,j) - ax(i,j+1) - ay(i,j))
// (wrap before cos is a no-op: cos is 2*pi periodic)
__global__ void k_pc(const float* __restrict__ x, float* __restrict__ ws) {
    int t = blockIdx.x * blockDim.x + threadIdx.x;
    if (t >= BQ * LL) return;
    int b = t / LL;
    int r = t - b * LL;
    int i = r >> 7;
    int j = r & (LQ - 1);
    const float* x0 = x + (size_t)(b * 4 + 0) * LL;
    const float* x1 = x0 + LL;
    const float* x2 = x0 + 2 * LL;
    const float* x3 = x0 + 3 * LL;
    int ip = wrapi(i + 1), jp = wrapi(j + 1);
    float ax  = atan2f(x1[i * LQ + j],  x0[i * LQ + j]);
    float ay  = atan2f(x3[i * LQ + j],  x2[i * LQ + j]);
    float axp = atan2f(x1[i * LQ + jp], x0[i * LQ + jp]);
    float ayp = atan2f(x3[ip * LQ + j], x2[ip * LQ + j]);
    float* pc = ws + WS_SEED_R + 2 * WS_BLL;
    pc[t] = cosf(ax + ayp - axp - ay);
}

// ---------------------------------------------------------------------------
// Kernel 4: pavg = 5-point average of pc
__global__ void k_pavg(float* __restrict__ ws) {
    int t = blockIdx.x * blockDim.x + threadIdx.x;
    if (t >= BQ * LL) return;
    int b = t / LL;
    int r = t - b * LL;
    int i = r >> 7;
    int j = r & (LQ - 1);
    const float* pc = ws + WS_SEED_R + 2 * WS_BLL;
    float* pv = ws + WS_SEED_R + 3 * WS_BLL;
    size_t boff = (size_t)b * LL;
    int ip = wrapi(i + 1), im = wrapi(i - 1);
    int jp = wrapi(j + 1), jm = wrapi(j - 1);
    float v = pc[boff + i * LQ + j]
            + pc[boff + im * LQ + j] + pc[boff + ip * LQ + j]
            + pc[boff + i * LQ + jm] + pc[boff + i * LQ + jp];
    pv[t] = v / 5.0f;
}

// ---------------------------------------------------------------------------
// Layer-1 tap helper: given link (lr,li) and the stencil point's
// (seed, pc, pavg), build transported f0 channels and accumulate with
// the 16x3 weight block sw (row-major [o][c]).
__device__ __forceinline__ void l1_tap(const float* __restrict__ sw,
                                       float lr, float li,
                                       float sr, float sim, float c_, float v_,
                                       float* ar, float* ai) {
    // transported seed = link * seed; channels = transported * (1, pc, pavg)
    float tr = lr * sr - li * sim;
    float ti = lr * sim + li * sr;
    float f0r0 = tr, f0r1 = tr * c_, f0r2 = tr * v_;
    float f0i0 = ti, f0i1 = ti * c_, f0i2 = ti * v_;
#pragma unroll
    for (int o = 0; o < H1; ++o) {
        float w0 = sw[o * 3 + 0], w1 = sw[o * 3 + 1], w2 = sw[o * 3 + 2];
        ar[o] += w0 * f0r0 + w1 * f0r1 + w2 * f0r2;
        ai[o] += w0 * f0i0 + w1 * f0i1 + w2 * f0i2;
    }
}

// Layer-2 tap helper: matvec (8x16, real) over f1 at LDS position pos, then
// complex-multiply by link and accumulate.
__device__ __forceinline__ void l2_tap(const float* __restrict__ sw,
                                       const float (*f1r)[NPTS],
                                       const float (*f1i)[NPTS],
                                       int pos, float lr, float li,
                                       float* a2r, float* a2i) {
    float sr[O2] = {0, 0, 0, 0, 0, 0, 0, 0};
    float si[O2] = {0, 0, 0, 0, 0, 0, 0, 0};
#pragma unroll
    for (int h = 0; h < H1; ++h) {
        float fr = f1r[h][pos], fi = f1i[h][pos];
#pragma unroll
        for (int o = 0; o < O2; ++o) {
            sr[o] = fmaf(sw[o * H1 + h], fr, sr[o]);
            si[o] = fmaf(sw[o * H1 + h], fi, si[o]);
        }
    }
#pragma unroll
    for (int o = 0; o < O2; ++o) {
        a2r[o] += lr * sr[o] - li * si[o];
        a2i[o] += lr * si[o] + li * sr[o];
    }
}

// ---------------------------------------------------------------------------
// Kernel 5: fused layer1 (+modrelu) -> LDS -> layer2 (+modrelu) -> readout.
// Block = 16x16 threads = one output tile; f1 computed on an 18x18 halo
// region in LDS (no 134 MB global round-trip for f1).
__global__ __launch_bounds__(256)
void k_fused(const float* __restrict__ x,
             const float* __restrict__ c1, const float* __restrict__ fw1,
             const float* __restrict__ bw1, const float* __restrict__ b1,
             const float* __restrict__ c2, const float* __restrict__ fw2,
             const float* __restrict__ bw2, const float* __restrict__ b2,
             const float* __restrict__ row, const float* __restrict__ rob,
             const float* __restrict__ ws, float* __restrict__ out) {
    __shared__ float s_f1r[H1][NPTS];
    __shared__ float s_f1i[H1][NPTS];
    __shared__ float s_w1[5][H1][3];   // taps: 0=center 1=fwd_x 2=bwd_x 3=fwd_y 4=bwd_y
    __shared__ float s_w2[5][O2][H1];
    __shared__ float s_b1[H1], s_b2[O2], s_ro[O2], s_rob[1];

    int tid = threadIdx.y * TILE + threadIdx.x;

    if (tid < H1 * 3) {
        int o = tid / 3, c = tid - o * 3;
        s_w1[0][o][c] = c1[tid];
        s_w1[1][o][c] = fw1[tid];
        s_w1[2][o][c] = bw1[tid];
        s_w1[3][o][c] = fw1[H1 * 3 + tid];
        s_w1[4][o][c] = bw1[H1 * 3 + tid];
    }
    if (tid < O2 * H1) {
        int o = tid / H1, h = tid - o * H1;
        s_w2[0][o][h] = c2[tid];
        s_w2[1][o][h] = fw2[tid];
        s_w2[2][o][h] = bw2[tid];
        s_w2[3][o][h] = fw2[O2 * H1 + tid];
        s_w2[4][o][h] = bw2[O2 * H1 + tid];
    }
    if (tid < H1) s_b1[tid] = b1[tid];
    if (tid < O2) { s_b2[tid] = b2[tid]; s_ro[tid] = row[tid]; }
    if (tid == 0) s_rob[0] = rob[0];
    __syncthreads();

    int b  = blockIdx.z;
    int i0 = blockIdx.y * TILE;
    int j0 = blockIdx.x * TILE;

    const float* seed_r = ws + WS_SEED_R;
    const float* seed_i = seed_r + WS_BLL;
    const float* pc     = seed_i + WS_BLL;
    const float* pv     = pc + WS_BLL;
    size_t boff = (size_t)b * LL;
    const float* x0 = x + (size_t)b * 4 * LL;
    const float* x1 = x0 + LL;
    const float* x2 = x0 + 2 * LL;
    const float* x3 = x0 + 3 * LL;

    // ---- Phase 1: f1 over the 18x18 halo region -> LDS ----
    for (int p = tid; p < NPTS; p += 256) {
        int ri = p / REG, rj = p - ri * REG;
        int gi = wrapi(i0 - 1 + ri);
        int gj = wrapi(j0 - 1 + rj);
        int gip = wrapi(gi + 1), gim = wrapi(gi - 1);
        int gjp = wrapi(gj + 1), gjm = wrapi(gj - 1);

        float ar[H1], ai[H1];
#pragma unroll
        for (int o = 0; o < H1; ++o) { ar[o] = 0.f; ai[o] = 0.f; }

        int idc = gi * LQ + gj;
        // center tap (link = 1)
        l1_tap(&s_w1[0][0][0], 1.f, 0.f,
               seed_r[boff + idc], seed_i[boff + idc], pc[boff + idc], pv[boff + idc],
               ar, ai);
        // fwd x: l0(gi,gj) * f0(gi+1, gj)
        {
            int idx = gip * LQ + gj;
            l1_tap(&s_w1[1][0][0], x0[idc], x1[idc],
                   seed_r[boff + idx], seed_i[boff + idx], pc[boff + idx], pv[boff + idx],
                   ar, ai);
        }
        // bwd x: conj(l0(gi-1,gj)) * f0(gi-1, gj)
        {
            int idl = gim * LQ + gj;
            l1_tap(&s_w1[2][0][0], x0[idl], -x1[idl],
                   seed_r[boff + idl], seed_i[boff + idl], pc[boff + idl], pv[boff + idl],
                   ar, ai);
        }
        // fwd y: l1(gi,gj) * f0(gi, gj+1)
        {
            int idx = gi * LQ + gjp;
            l1_tap(&s_w1[3][0][0], x2[idc], x3[idc],
                   seed_r[boff + idx], seed_i[boff + idx], pc[boff + idx], pv[boff + idx],
                   ar, ai);
        }
        // bwd y: conj(l1(gi,gj-1)) * f0(gi, gj-1)
        {
            int idl = gi * LQ + gjm;
            l1_tap(&s_w1[4][0][0], x2[idl], -x3[idl],
                   seed_r[boff + idl], seed_i[boff + idl], pc[boff + idl], pv[boff + idl],
                   ar, ai);
        }

        // modrelu1 (+ store to LDS)
#pragma unroll
        for (int o = 0; o < H1; ++o) {
            float m   = sqrtf(ar[o] * ar[o] + ai[o] * ai[o] + 1e-12f);
            float act = fmaxf(m + s_b1[o], 0.f);
            float s   = act / fmaxf(m, 1e-12f);
            s_f1r[o][p] = ar[o] * s;
            s_f1i[o][p] = ai[o] * s;
        }
    }
    __syncthreads();

    // ---- Phase 2: layer2 + modrelu + readout ----
    int ty = threadIdx.y, tx = threadIdx.x;
    int i = i0 + ty, j = j0 + tx;
    int pcen = (ty + 1) * REG + (tx + 1);
    int im = wrapi(i - 1), jm = wrapi(j - 1);

    float a2r[O2] = {0, 0, 0, 0, 0, 0, 0, 0};
    float a2i[O2] = {0, 0, 0, 0, 0, 0, 0, 0};

    int idc = i * LQ + j;
    // center
    l2_tap(&s_w2[0][0][0], s_f1r, s_f1i, pcen, 1.f, 0.f, a2r, a2i);
    // fwd x: l0(i,j) * f1(i+1,j)
    l2_tap(&s_w2[1][0][0], s_f1r, s_f1i, pcen + REG, x0[idc], x1[idc], a2r, a2i);
    // bwd x: conj(l0(i-1,j)) * f1(i-1,j)
    l2_tap(&s_w2[2][0][0], s_f1r, s_f1i, pcen - REG, x0[im * LQ + j], -x1[im * LQ + j], a2r, a2i);
    // fwd y: l1(i,j) * f1(i,j+1)
    l2_tap(&s_w2[3][0][0], s_f1r, s_f1i, pcen + 1, x2[idc], x3[idc], a2r, a2i);
    // bwd y: conj(l1(i,j-1)) * f1(i,j-1)
    l2_tap(&s_w2[4][0][0], s_f1r, s_f1i, pcen - 1, x2[i * LQ + jm], -x3[i * LQ + jm], a2r, a2i);

    // modrelu2 + readout
    float res = s_rob[0];
#pragma unroll
    for (int o = 0; o < O2; ++o) {
        float m   = sqrtf(a2r[o] * a2r[o] + a2i[o] * a2i[o] + 1e-12f);
        float act = fmaxf(m + s_b2[o], 0.f);
        float s   = act / fmaxf(m, 1e-12f);
        float fr  = a2r[o] * s, fi = a2i[o] * s;
        res = fmaf(s_ro[o], fr * fr + fi * fi, res);
    }
    out[boff + idc] = res;
}

// ---------------------------------------------------------------------------
extern "C" void kernel_launch(void* const* d_in, const int* in_sizes, int n_in,
                              void* d_out, int out_size, void* d_ws, size_t ws_size,
                              hipStream_t stream) {
    const float* x   = (const float*)d_in[0];
    const float* c1  = (const float*)d_in[1];
    const float* fw1 = (const float*)d_in[2];
    const float* bw1 = (const float*)d_in[3];
    const float* b1  = (const float*)d_in[4];
    const float* c2  = (const float*)d_in[5];
    const float* fw2 = (const float*)d_in[6];
    const float* bw2 = (const float*)d_in[7];
    const float* b2  = (const float*)d_in[8];
    const float* ro  = (const float*)d_in[9];
    const float* rob = (const float*)d_in[10];
    float* out = (float*)d_out;
    float* ws  = (float*)d_ws;

    k_xaxis<<<1, 64, 0, stream>>>(x, ws);
    k_seed<<<(BQ * LQ + 255) / 256, 256, 0, stream>>>(x, ws);
    k_pc<<<(BQ * LL + 255) / 256, 256, 0, stream>>>(x, ws);
    k_pavg<<<(BQ * LL + 255) / 256, 256, 0, stream>>>(ws);

    dim3 grid(LQ / TILE, LQ / TILE, BQ);   // 8 x 8 x 64
    dim3 blk(TILE, TILE, 1);               // 256 threads
    k_fused<<<grid, blk, 0, stream>>>(x, c1, fw1, bw1, b1, c2, fw2, bw2, b2,
                                      ro, rob, ws, out);
}

// Round 2
// 200.486 us; speedup vs baseline: 1.8931x; 1.8931x over previous
//
#include <hip/hip_runtime.h>
#include <math.h>

// B=64, L=128, H=16, O=8
#define LQ   128
#define BQ   64
#define LL   (LQ*LQ)
#define H1   16
#define O2   8
#define TILE 16
#define REG  18          // TILE + 2 halo (f1 region)
#define NPTS (REG*REG)   // 324
#define AXR  19
#define AXN  (AXR*AXR)   // 361

__device__ __forceinline__ int wrapi(int v) { return v & (LQ - 1); }

// ws layout (floats):
//   [0 .. 16384)   xaxis as float2[BQ][LQ]
//   [16384 .. )    feat4 as float4[BQ*LL] = (seed_r, seed_i, pc, pavg)
#define WS_FEAT 16384

__global__ void k_scanx(const float* __restrict__ x, float* __restrict__ ws) {
    int b = blockIdx.x;
    int l = threadIdx.x;          // 64 threads = 1 wave
    const float* x0 = x + (size_t)b * 4 * LL;
    const float* x1 = x0 + LL;
    float ur0 = x0[(2 * l) * LQ],     ui0 = x1[(2 * l) * LQ];
    float ur1 = x0[(2 * l + 1) * LQ], ui1 = x1[(2 * l + 1) * LQ];
    float pr = ur0 * ur1 - ui0 * ui1;
    float pi = ur0 * ui1 + ui0 * ur1;
    for (int d = 1; d < 64; d <<= 1) {
        float qr = __shfl_up(pr, d, 64);
        float qi = __shfl_up(pi, d, 64);
        if (l >= d) {
            float nr = qr * pr - qi * pi;
            float ni = qr * pi + qi * pr;
            pr = nr; pi = ni;
        }
    }
    float er = __shfl_up(pr, 1, 64);
    float ei = __shfl_up(pi, 1, 64);
    if (l == 0) { er = 1.f; ei = 0.f; }
    float e1r = er * ur0 - ei * ui0;
    float e1i = er * ui0 + ei * ur0;
    ((float4*)ws)[b * 64 + l] = make_float4(er, ei, e1r, e1i);
}

__global__ void k_seed(const float* __restrict__ x, float* __restrict__ ws) {
    int gt = blockIdx.x * blockDim.x + threadIdx.x;
    int wave = gt >> 6;
    int l = gt & 63;
    if (wave >= BQ * LQ) return;
    int b = wave >> 7, i = wave & (LQ - 1);
    const float* yr = x + (size_t)(b * 4 + 2) * LL + (size_t)i * LQ;
    const float* yi = yr + LL;
    float ur0 = yr[2 * l],     ui0 = yi[2 * l];
    float ur1 = yr[2 * l + 1], ui1 = yi[2 * l + 1];
    float pr = ur0 * ur1 - ui0 * ui1;
    float pi = ur0 * ui1 + ui0 * ur1;
    for (int d = 1; d < 64; d <<= 1) {
        float qr = __shfl_up(pr, d, 64);
        float qi = __shfl_up(pi, d, 64);
        if (l >= d) {
            float nr = qr * pr - qi * pi;
            float ni = qr * pi + qi * pr;
            pr = nr; pi = ni;
        }
    }
    float er = __shfl_up(pr, 1, 64);
    float ei = __shfl_up(pi, 1, 64);
    if (l == 0) { er = 1.f; ei = 0.f; }
    float2 ch = ((const float2*)ws)[b * LQ + i];
    float s0r = ch.x * er - ch.y * ei;
    float s0i = ch.x * ei + ch.y * er;
    float s1r = s0r * ur0 - s0i * ui0;
    float s1i = s0r * ui0 + s0i * ur0;
    float4* feat = (float4*)(ws + WS_FEAT);
    size_t base = (size_t)b * LL + (size_t)i * LQ;
    float2* f0 = (float2*)&feat[base + 2 * l];
    f0[0] = make_float2(s0r, -s0i);
    f0[2] = make_float2(s1r, -s1i);
}

__global__ __launch_bounds__(256)
void k_prep(const float* __restrict__ x, float* __restrict__ ws) {
    __shared__ float s_ax[AXN], s_ay[AXN];
    __shared__ float s_pc[NPTS];
    int tid = threadIdx.x;
    int b = blockIdx.z, i0 = blockIdx.y * TILE, j0 = blockIdx.x * TILE;
    const float* x0 = x + (size_t)b * 4 * LL;
    const float* x1 = x0 + LL;
    const float* x2 = x0 + 2 * LL;
    const float* x3 = x0 + 3 * LL;

    for (int p = tid; p < AXN; p += 256) {
        int ri = p / AXR, rj = p - ri * AXR;
        int gi = wrapi(i0 - 1 + ri), gj = wrapi(j0 - 1 + rj);
        int idx = gi * LQ + gj;
        s_ax[p] = atan2f(x1[idx], x0[idx]);
        s_ay[p] = atan2f(x3[idx], x2[idx]);
    }
    __syncthreads();
    for (int p = tid; p < NPTS; p += 256) {
        int ri = p / REG, rj = p - ri * REG;
        int a = ri * AXR + rj;
        s_pc[p] = cosf(s_ax[a] + s_ay[a + AXR] - s_ax[a + 1] - s_ay[a]);
    }
    __syncthreads();
    int ty = tid >> 4, tx = tid & 15;
    int i = i0 + ty, j = j0 + tx;
    int c = (ty + 1) * REG + (tx + 1);
    float pcc  = s_pc[c];
    float pavg = (pcc + s_pc[c - REG] + s_pc[c + REG] + s_pc[c - 1] + s_pc[c + 1]) / 5.0f;
    float4* feat = (float4*)(ws + WS_FEAT);
    float2* fz = (float2*)&feat[(size_t)b * LL + (size_t)i * LQ + j];
    fz[1] = make_float2(pcc, pavg);
}

__device__ __forceinline__ void l2_tap(const float* __restrict__ w,
                                       const float2 (*__restrict__ f1)[NPTS],
                                       int pos, float lr, float li,
                                       float* a2r, float* a2i) {
    float sr[O2] = {0, 0, 0, 0, 0, 0, 0, 0};
    float si[O2] = {0, 0, 0, 0, 0, 0, 0, 0};
#pragma unroll
    for (int h = 0; h < H1; ++h) {
        float2 f = f1[h][pos];
#pragma unroll
        for (int o = 0; o < O2; ++o) {
            float ww = w[o * H1 + h];
            sr[o] = fmaf(ww, f.x, sr[o]);
            si[o] = fmaf(ww, f.y, si[o]);
        }
    }
#pragma unroll
    for (int o = 0; o < O2; ++o) {
        a2r[o] += lr * sr[o] - li * si[o];
        a2i[o] += lr * si[o] + li * sr[o];
    }
}

__global__ __launch_bounds__(256)
void k_fused(const float* __restrict__ x,
             const float* __restrict__ c1, const float* __restrict__ fw1,
             const float* __restrict__ bw1, const float* __restrict__ b1,
             const float* __restrict__ c2, const float* __restrict__ fw2,
             const float* __restrict__ bw2, const float* __restrict__ b2,
             const float* __restrict__ ro, const float* __restrict__ rob,
             const float* __restrict__ ws, float* __restrict__ out) {
    __shared__ float2 s_f1[H1][NPTS];   // 41.5 KB
    int tid = threadIdx.x;
    int b = blockIdx.z, i0 = blockIdx.y * TILE, j0 = blockIdx.x * TILE;
    const float* x0 = x + (size_t)b * 4 * LL;
    const float* x1 = x0 + LL;
    const float* x2 = x0 + 2 * LL;
    const float* x3 = x0 + 3 * LL;
    const float4* feat = (const float4*)(ws + WS_FEAT) + (size_t)b * LL;

    for (int p = tid; p < NPTS; p += 256) {
        int ri = p / REG, rj = p - ri * REG;
        int gi = wrapi(i0 - 1 + ri), gj = wrapi(j0 - 1 + rj);
        int gip = wrapi(gi + 1), gim = wrapi(gi - 1);
        int gjp = wrapi(gj + 1), gjm = wrapi(gj - 1);
        int idc = gi * LQ + gj;
        float4 C  = feat[idc];
        float4 XP = feat[gip * LQ + gj];
        float4 XM = feat[gim * LQ + gj];
        float4 YP = feat[gi * LQ + gjp];
        float4 YM = feat[gi * LQ + gjm];
        float lxr = x0[idc], lxi = x1[idc];
        float lyr = x2[idc], lyi = x3[idc];
        int idxm = gim * LQ + gj, idym = gi * LQ + gjm;
        float mxr = x0[idxm], mxi = -x1[idxm];
        float myr = x2[idym], myi = -x3[idym];

        float tr[5], ti[5], tc[5], tv[5];
        tr[0] = C.x;                       ti[0] = C.y;                       tc[0] = C.z; tv[0] = C.w;
        tr[1] = lxr * XP.x - lxi * XP.y;   ti[1] = lxr * XP.y + lxi * XP.x;   tc[1] = XP.z; tv[1] = XP.w;
        tr[2] = mxr * XM.x - mxi * XM.y;   ti[2] = mxr * XM.y + mxi * XM.x;   tc[2] = XM.z; tv[2] = XM.w;
        tr[3] = lyr * YP.x - lyi * YP.y;   ti[3] = lyr * YP.y + lyi * YP.x;   tc[3] = YP.z; tv[3] = YP.w;
        tr[4] = myr * YM.x - myi * YM.y;   ti[4] = myr * YM.y + myi * YM.x;   tc[4] = YM.z; tv[4] = YM.w;

#pragma unroll
        for (int o = 0; o < H1; ++o) {
            float m0 = fmaf(c1[o * 3 + 2], tv[0], fmaf(c1[o * 3 + 1], tc[0], c1[o * 3]));
            float m1 = fmaf(fw1[o * 3 + 2], tv[1], fmaf(fw1[o * 3 + 1], tc[1], fw1[o * 3]));
            float m2 = fmaf(bw1[o * 3 + 2], tv[2], fmaf(bw1[o * 3 + 1], tc[2], bw1[o * 3]));
            float m3 = fmaf(fw1[48 + o * 3 + 2], tv[3], fmaf(fw1[48 + o * 3 + 1], tc[3], fw1[48 + o * 3]));
            float m4 = fmaf(bw1[48 + o * 3 + 2], tv[4], fmaf(bw1[48 + o * 3 + 1], tc[4], bw1[48 + o * 3]));
            float ar = m0 * tr[0]; float ai = m0 * ti[0];
            ar = fmaf(m1, tr[1], ar); ai = fmaf(m1, ti[1], ai);
            ar = fmaf(m2, tr[2], ar); ai = fmaf(m2, ti[2], ai);
            ar = fmaf(m3, tr[3], ar); ai = fmaf(m3, ti[3], ai);
            ar = fmaf(m4, tr[4], ar); ai = fmaf(m4, ti[4], ai);
            float q = fmaf(ar, ar, ai * ai) + 1e-12f;
            float s = fmaxf(fmaf(b1[o], __frsqrt_rn(q), 1.f), 0.f);
            s_f1[o][p] = make_float2(ar * s, ai * s);
        }
    }
    __syncthreads();

    int ty = tid >> 4, tx = tid & 15;
    int i = i0 + ty, j = j0 + tx;
    int im = wrapi(i - 1), jm = wrapi(j - 1);
    int idc = i * LQ + j;
    float lxr = x0[idc], lxi = x1[idc];
    float lyr = x2[idc], lyi = x3[idc];
    float mxr = x0[im * LQ + j], mxi = -x1[im * LQ + j];
    float myr = x2[i * LQ + jm], myi = -x3[i * LQ + jm];
    int pc_ = (ty + 1) * REG + (tx + 1);

    float a2r[O2] = {0, 0, 0, 0, 0, 0, 0, 0};
    float a2i[O2] = {0, 0, 0, 0, 0, 0, 0, 0};
    l2_tap(c2,          s_f1, pc_,       1.f, 0.f, a2r, a2i);
    l2_tap(fw2,         s_f1, pc_ + REG, lxr, lxi, a2r, a2i);
    l2_tap(bw2,         s_f1, pc_ - REG, mxr, mxi, a2r, a2i);
    l2_tap(fw2 + O2*H1, s_f1, pc_ + 1,   lyr, lyi, a2r, a2i);
    l2_tap(bw2 + O2*H1, s_f1, pc_ - 1,   myr, myi, a2r, a2i);

    float res = rob[0];
#pragma unroll
    for (int o = 0; o < O2; ++o) {
        float q = fmaf(a2r[o], a2r[o], a2i[o] * a2i[o]);
        float s = fmaxf(fmaf(b2[o], __frsqrt_rn(q + 1e-12f), 1.f), 0.f);
        res = fmaf(ro[o], s * s * q, res);
    }
    out[(size_t)b * LL + idc] = res;
}

extern "C" void kernel_launch(void* const* d_in, const int* in_sizes, int n_in,
                              void* d_out, int out_size, void* d_ws, size_t ws_size,
                              hipStream_t stream) {
    const float* x   = (const float*)d_in[0];
    const float* c1  = (const float*)d_in[1];
    const float* fw1 = (const float*)d_in[2];
    const float* bw1 = (const float*)d_in[3];
    const float* b1  = (const float*)d_in[4];
    const float* c2  = (const float*)d_in[5];
    const float* fw2 = (const float*)d_in[6];
    const float* bw2 = (const float*)d_in[7];
    const float* b2  = (const float*)d_in[8];
    const float* ro  = (const float*)d_in[9];
    const float* rob = (const float*)d_in[10];
    float* out = (float*)d_out;
    float* ws  = (float*)d_ws;

    k_scanx<<<BQ, 64, 0, stream>>>(x, ws);
    k_seed<<<(BQ * LQ * 64) / 256, 256, 0, stream>>>(x, ws);
    dim3 grid(LQ / TILE, LQ / TILE, BQ);
    k_prep<<<grid, 256, 0, stream>>>(x, ws);
    k_fused<<<grid, 256, 0, stream>>>(x, c1, fw1, bw1, b1, c2, fw2, bw2, b2,
                                      ro, rob, ws, out);
}

// Round 3
// 198.343 us; speedup vs baseline: 1.9136x; 1.0108x over previous
//
#include <hip/hip_runtime.h>
#include <math.h>

// B=64, L=128, H=16, O=8
#define LQ   128
#define BQ   64
#define LL   (LQ*LQ)
#define H1   16
#define O2   8
#define TILE 16
#define REG  18          // f1 region (origin i0-1)
#define NPTS (REG*REG)   // 324
#define PVR  20          // pavg region (origin i0-2)
#define PVN  (PVR*PVR)   // 400
#define PCR  22          // pc region (origin i0-3)
#define PCN  (PCR*PCR)   // 484

__device__ __forceinline__ int wrapi(int v) { return v & (LQ - 1); }

// ws layout (floats):
//   [0 .. 16384)      xaxis as float4[BQ][64]  (pairs of complex)
//   [16384 .. )       seed as float2[BQ*LL]    (8 MB)
#define WS_SEED 16384

// ---------------------------------------------------------------------------
// Wave-parallel complex prefix product along the x-axis (column j=0).
__global__ void k_scanx(const float* __restrict__ x, float* __restrict__ ws) {
    int b = blockIdx.x;
    int l = threadIdx.x;          // 64 threads = 1 wave
    const float* x0 = x + (size_t)b * 4 * LL;
    const float* x1 = x0 + LL;
    float ur0 = x0[(2 * l) * LQ],     ui0 = x1[(2 * l) * LQ];
    float ur1 = x0[(2 * l + 1) * LQ], ui1 = x1[(2 * l + 1) * LQ];
    float pr = ur0 * ur1 - ui0 * ui1;
    float pi = ur0 * ui1 + ui0 * ur1;
    for (int d = 1; d < 64; d <<= 1) {
        float qr = __shfl_up(pr, d, 64);
        float qi = __shfl_up(pi, d, 64);
        if (l >= d) {
            float nr = qr * pr - qi * pi;
            float ni = qr * pi + qi * pr;
            pr = nr; pi = ni;
        }
    }
    float er = __shfl_up(pr, 1, 64);
    float ei = __shfl_up(pi, 1, 64);
    if (l == 0) { er = 1.f; ei = 0.f; }
    float e1r = er * ur0 - ei * ui0;
    float e1i = er * ui0 + ei * ur0;
    ((float4*)ws)[b * 64 + l] = make_float4(er, ei, e1r, e1i);
}

// ---------------------------------------------------------------------------
// Wave-per-row scan along j; writes conj(path) as seed float2 (float4 stores).
__global__ void k_seed(const float* __restrict__ x, float* __restrict__ ws) {
    int gt = blockIdx.x * blockDim.x + threadIdx.x;
    int wave = gt >> 6;
    int l = gt & 63;
    if (wave >= BQ * LQ) return;
    int b = wave >> 7, i = wave & (LQ - 1);
    const float* yr = x + (size_t)(b * 4 + 2) * LL + (size_t)i * LQ;
    const float* yi = yr + LL;
    float ur0 = yr[2 * l],     ui0 = yi[2 * l];
    float ur1 = yr[2 * l + 1], ui1 = yi[2 * l + 1];
    float pr = ur0 * ur1 - ui0 * ui1;
    float pi = ur0 * ui1 + ui0 * ur1;
    for (int d = 1; d < 64; d <<= 1) {
        float qr = __shfl_up(pr, d, 64);
        float qi = __shfl_up(pi, d, 64);
        if (l >= d) {
            float nr = qr * pr - qi * pi;
            float ni = qr * pi + qi * pr;
            pr = nr; pi = ni;
        }
    }
    float er = __shfl_up(pr, 1, 64);
    float ei = __shfl_up(pi, 1, 64);
    if (l == 0) { er = 1.f; ei = 0.f; }
    float2 ch = ((const float2*)ws)[b * LQ + i];   // xaxis[b][i], wave-uniform
    float s0r = ch.x * er - ch.y * ei;
    float s0i = ch.x * ei + ch.y * er;
    float s1r = s0r * ur0 - s0i * ui0;
    float s1i = s0r * ui0 + s0i * ur0;
    // coalesced float4 store covering seed[2l], seed[2l+1]
    float4* seed4 = (float4*)(ws + WS_SEED);
    seed4[((size_t)b * LL + (size_t)i * LQ) / 2 + l] =
        make_float4(s0r, -s0i, s1r, -s1i);
}

// ---------------------------------------------------------------------------
// Layer-2 tap: 8x16 real matvec over f1 (complex) + rotation by link.
__device__ __forceinline__ void l2_tap(const float* __restrict__ w,
                                       const float2 (*__restrict__ f1)[NPTS],
                                       int pos, float lr, float li,
                                       float* a2r, float* a2i) {
    float sr[O2] = {0, 0, 0, 0, 0, 0, 0, 0};
    float si[O2] = {0, 0, 0, 0, 0, 0, 0, 0};
#pragma unroll
    for (int h = 0; h < H1; ++h) {
        float2 f = f1[h][pos];
#pragma unroll
        for (int o = 0; o < O2; ++o) {
            float ww = w[o * H1 + h];
            sr[o] = fmaf(ww, f.x, sr[o]);
            si[o] = fmaf(ww, f.y, si[o]);
        }
    }
#pragma unroll
    for (int o = 0; o < O2; ++o) {
        a2r[o] += lr * sr[o] - li * si[o];
        a2i[o] += lr * si[o] + li * sr[o];
    }
}

// ---------------------------------------------------------------------------
// Fused: plaquette (pc/pavg) -> layer1+modrelu -> LDS -> layer2+modrelu -> out
__global__ __launch_bounds__(256)
void k_main(const float* __restrict__ x,
            const float* __restrict__ c1, const float* __restrict__ fw1,
            const float* __restrict__ bw1, const float* __restrict__ b1,
            const float* __restrict__ c2, const float* __restrict__ fw2,
            const float* __restrict__ bw2, const float* __restrict__ b2,
            const float* __restrict__ ro, const float* __restrict__ rob,
            const float* __restrict__ ws, float* __restrict__ out) {
    __shared__ float2 s_f1[H1][NPTS];   // 41.5 KB
    __shared__ float s_pc[PCN];         // 1.9 KB
    __shared__ float s_pv[PVN];         // 1.6 KB
    int tid = threadIdx.x;
    int b = blockIdx.z, i0 = blockIdx.y * TILE, j0 = blockIdx.x * TILE;
    const float* x0 = x + (size_t)b * 4 * LL;
    const float* x1 = x0 + LL;
    const float* x2 = x0 + 2 * LL;
    const float* x3 = x0 + 3 * LL;
    const float2* seed = (const float2*)(ws + WS_SEED) + (size_t)b * LL;

    // ---- Phase B: pc on 22x22 via complex plaquette product (no atan2) ----
    for (int p = tid; p < PCN; p += 256) {
        int ri = p / PCR, rj = p - ri * PCR;
        int gi = wrapi(i0 - 3 + ri), gj = wrapi(j0 - 3 + rj);
        int gip = wrapi(gi + 1), gjp = wrapi(gj + 1);
        int ic = gi * LQ + gj;
        float u1r = x0[ic],            u1i = x1[ic];             // ux(i,j)
        float u2r = x2[gip * LQ + gj], u2i = x3[gip * LQ + gj];  // uy(i+1,j)
        float u3r = x0[gi * LQ + gjp], u3i = -x1[gi * LQ + gjp]; // conj ux(i,j+1)
        float u4r = x2[ic],            u4i = -x3[ic];            // conj uy(i,j)
        float ar = u1r * u2r - u1i * u2i, ai = u1r * u2i + u1i * u2r;
        float br = ar * u3r - ai * u3i,   bi = ar * u3i + ai * u3r;
        float zr = br * u4r - bi * u4i,   zi = br * u4i + bi * u4r;
        s_pc[p] = zr * __frsqrt_rn(fmaf(zr, zr, zi * zi) + 1e-30f);
    }
    __syncthreads();

    // ---- Phase B2: pavg on 20x20 ----
    for (int p = tid; p < PVN; p += 256) {
        int ri = p / PVR, rj = p - ri * PVR;
        int c = (ri + 1) * PCR + (rj + 1);
        s_pv[p] = (s_pc[c] + s_pc[c - PCR] + s_pc[c + PCR]
                 + s_pc[c - 1] + s_pc[c + 1]) * 0.2f;
    }
    __syncthreads();

    // ---- Phase C: layer1 + modrelu on 18x18 -> LDS ----
    for (int p = tid; p < NPTS; p += 256) {
        int ri = p / REG, rj = p - ri * REG;
        int di = ri - 1, dj = rj - 1;
        int gi = wrapi(i0 + di), gj = wrapi(j0 + dj);
        int gip = wrapi(gi + 1), gim = wrapi(gi - 1);
        int gjp = wrapi(gj + 1), gjm = wrapi(gj - 1);
        int idc = gi * LQ + gj;
        float2 SC  = seed[idc];
        float2 SXP = seed[gip * LQ + gj];
        float2 SXM = seed[gim * LQ + gj];
        float2 SYP = seed[gi * LQ + gjp];
        float2 SYM = seed[gi * LQ + gjm];
        float lxr = x0[idc], lxi = x1[idc];
        float lyr = x2[idc], lyi = x3[idc];
        int ixm = gim * LQ + gj, iym = gi * LQ + gjm;
        float mxr = x0[ixm], mxi = -x1[ixm];
        float myr = x2[iym], myi = -x3[iym];

        int cb = (di + 3) * PCR + (dj + 3);
        int vb = (di + 2) * PVR + (dj + 2);

        float tr[5], ti[5], tc[5], tv[5];
        tr[0] = SC.x;                      ti[0] = SC.y;
        tc[0] = s_pc[cb];                  tv[0] = s_pv[vb];
        tr[1] = lxr * SXP.x - lxi * SXP.y; ti[1] = lxr * SXP.y + lxi * SXP.x;
        tc[1] = s_pc[cb + PCR];            tv[1] = s_pv[vb + PVR];
        tr[2] = mxr * SXM.x - mxi * SXM.y; ti[2] = mxr * SXM.y + mxi * SXM.x;
        tc[2] = s_pc[cb - PCR];            tv[2] = s_pv[vb - PVR];
        tr[3] = lyr * SYP.x - lyi * SYP.y; ti[3] = lyr * SYP.y + lyi * SYP.x;
        tc[3] = s_pc[cb + 1];              tv[3] = s_pv[vb + 1];
        tr[4] = myr * SYM.x - myi * SYM.y; ti[4] = myr * SYM.y + myi * SYM.x;
        tc[4] = s_pc[cb - 1];              tv[4] = s_pv[vb - 1];

#pragma unroll
        for (int o = 0; o < H1; ++o) {
            float m0 = fmaf(c1[o * 3 + 2], tv[0], fmaf(c1[o * 3 + 1], tc[0], c1[o * 3]));
            float m1 = fmaf(fw1[o * 3 + 2], tv[1], fmaf(fw1[o * 3 + 1], tc[1], fw1[o * 3]));
            float m2 = fmaf(bw1[o * 3 + 2], tv[2], fmaf(bw1[o * 3 + 1], tc[2], bw1[o * 3]));
            float m3 = fmaf(fw1[48 + o * 3 + 2], tv[3], fmaf(fw1[48 + o * 3 + 1], tc[3], fw1[48 + o * 3]));
            float m4 = fmaf(bw1[48 + o * 3 + 2], tv[4], fmaf(bw1[48 + o * 3 + 1], tc[4], bw1[48 + o * 3]));
            float ar = m0 * tr[0]; float ai = m0 * ti[0];
            ar = fmaf(m1, tr[1], ar); ai = fmaf(m1, ti[1], ai);
            ar = fmaf(m2, tr[2], ar); ai = fmaf(m2, ti[2], ai);
            ar = fmaf(m3, tr[3], ar); ai = fmaf(m3, ti[3], ai);
            ar = fmaf(m4, tr[4], ar); ai = fmaf(m4, ti[4], ai);
            float q = fmaf(ar, ar, ai * ai) + 1e-12f;
            float s = fmaxf(fmaf(b1[o], __frsqrt_rn(q), 1.f), 0.f);
            s_f1[o][p] = make_float2(ar * s, ai * s);
        }
    }
    __syncthreads();

    // ---- Phase D: layer2 + modrelu + readout ----
    int ty = tid >> 4, tx = tid & 15;
    int i = i0 + ty, j = j0 + tx;
    int im = wrapi(i - 1), jm = wrapi(j - 1);
    int idc = i * LQ + j;
    float lxr = x0[idc], lxi = x1[idc];
    float lyr = x2[idc], lyi = x3[idc];
    float mxr = x0[im * LQ + j], mxi = -x1[im * LQ + j];
    float myr = x2[i * LQ + jm], myi = -x3[i * LQ + jm];
    int pc_ = (ty + 1) * REG + (tx + 1);

    float a2r[O2] = {0, 0, 0, 0, 0, 0, 0, 0};
    float a2i[O2] = {0, 0, 0, 0, 0, 0, 0, 0};
    l2_tap(c2,            s_f1, pc_,       1.f, 0.f, a2r, a2i);
    l2_tap(fw2,           s_f1, pc_ + REG, lxr, lxi, a2r, a2i);
    l2_tap(bw2,           s_f1, pc_ - REG, mxr, mxi, a2r, a2i);
    l2_tap(fw2 + O2 * H1, s_f1, pc_ + 1,   lyr, lyi, a2r, a2i);
    l2_tap(bw2 + O2 * H1, s_f1, pc_ - 1,   myr, myi, a2r, a2i);

    float res = rob[0];
#pragma unroll
    for (int o = 0; o < O2; ++o) {
        float q = fmaf(a2r[o], a2r[o], a2i[o] * a2i[o]);
        float s = fmaxf(fmaf(b2[o], __frsqrt_rn(q + 1e-12f), 1.f), 0.f);
        res = fmaf(ro[o], s * s * q, res);
    }
    out[(size_t)b * LL + idc] = res;
}

// ---------------------------------------------------------------------------
extern "C" void kernel_launch(void* const* d_in, const int* in_sizes, int n_in,
                              void* d_out, int out_size, void* d_ws, size_t ws_size,
                              hipStream_t stream) {
    const float* x   = (const float*)d_in[0];
    const float* c1  = (const float*)d_in[1];
    const float* fw1 = (const float*)d_in[2];
    const float* bw1 = (const float*)d_in[3];
    const float* b1  = (const float*)d_in[4];
    const float* c2  = (const float*)d_in[5];
    const float* fw2 = (const float*)d_in[6];
    const float* bw2 = (const float*)d_in[7];
    const float* b2  = (const float*)d_in[8];
    const float* ro  = (const float*)d_in[9];
    const float* rob = (const float*)d_in[10];
    float* out = (float*)d_out;
    float* ws  = (float*)d_ws;

    k_scanx<<<BQ, 64, 0, stream>>>(x, ws);
    k_seed<<<(BQ * LQ * 64) / 256, 256, 0, stream>>>(x, ws);
    dim3 grid(LQ / TILE, LQ / TILE, BQ);
    k_main<<<grid, 256, 0, stream>>>(x, c1, fw1, bw1, b1, c2, fw2, bw2, b2,
                                     ro, rob, ws, out);
}

// Round 4
// 165.308 us; speedup vs baseline: 2.2960x; 1.1998x over previous
//
#include <hip/hip_runtime.h>
#include <math.h>

// B=64, L=128, H=16, O=8
#define LQ   128
#define BQ   64
#define LL   (LQ*LQ)
#define H1   16
#define O2   8
#define TILE 16
#define REG  18          // f1 region (origin i0-1)
#define NPTS (REG*REG)   // 324
#define PVR  20          // pavg region (origin i0-2)
#define PVN  (PVR*PVR)   // 400
#define PCR  22          // pc region (origin i0-3)
#define PCN  (PCR*PCR)   // 484
#define LKR  23          // link region (origin i0-3)
#define LKN  (LKR*LKR)   // 529

typedef float f2 __attribute__((ext_vector_type(2)));

__device__ __forceinline__ int wrapi(int v) { return v & (LQ - 1); }

// ws layout: seed as float2[BQ*LL] at offset 0 (8 MB)

// ---------------------------------------------------------------------------
// Fused x-scan + row scans. Block = (b, rq); 4 waves; wave handles 4 rows.
// Every wave redundantly computes the 128-long x-axis prefix product (cheap),
// then does its rows' y-scans and writes conj(seed) with float4 stores.
__global__ __launch_bounds__(256)
void k_scan(const float* __restrict__ x, float* __restrict__ ws) {
    int blk = blockIdx.x;
    int b = blk >> 3, rq = blk & 7;
    int l = threadIdx.x & 63, w = threadIdx.x >> 6;
    const float* x0 = x + (size_t)b * 4 * LL;
    const float* x1 = x0 + LL;

    // x-axis scan over column j=0 (rows 2l, 2l+1 per lane)
    float ur0 = x0[(2 * l) * LQ],     ui0 = x1[(2 * l) * LQ];
    float ur1 = x0[(2 * l + 1) * LQ], ui1 = x1[(2 * l + 1) * LQ];
    float pr = ur0 * ur1 - ui0 * ui1;
    float pi = ur0 * ui1 + ui0 * ur1;
    for (int d = 1; d < 64; d <<= 1) {
        float qr = __shfl_up(pr, d, 64);
        float qi = __shfl_up(pi, d, 64);
        if (l >= d) {
            float nr = qr * pr - qi * pi;
            float ni = qr * pi + qi * pr;
            pr = nr; pi = ni;
        }
    }
    float er = __shfl_up(pr, 1, 64);
    float ei = __shfl_up(pi, 1, 64);
    if (l == 0) { er = 1.f; ei = 0.f; }
    float e1r = er * ur0 - ei * ui0;          // exclusive prefix for row 2l+1
    float e1i = er * ui0 + ei * ur0;

    const float* yrp = x + (size_t)(b * 4 + 2) * LL;
    const float* yip = yrp + LL;
    float4* seed4 = (float4*)ws;

    for (int k = 0; k < 4; ++k) {
        int i = rq * 16 + w * 4 + k;          // wave-uniform row
        float cxr = __shfl((i & 1) ? e1r : er, i >> 1, 64);
        float cxi = __shfl((i & 1) ? e1i : ei, i >> 1, 64);
        const float* yr = yrp + (size_t)i * LQ;
        const float* yi = yip + (size_t)i * LQ;
        float vr0 = yr[2 * l],     vi0 = yi[2 * l];
        float vr1 = yr[2 * l + 1], vi1 = yi[2 * l + 1];
        float sr = vr0 * vr1 - vi0 * vi1;
        float si = vr0 * vi1 + vi0 * vr1;
        for (int d = 1; d < 64; d <<= 1) {
            float qr = __shfl_up(sr, d, 64);
            float qi = __shfl_up(si, d, 64);
            if (l >= d) {
                float nr = qr * sr - qi * si;
                float ni = qr * si + qi * sr;
                sr = nr; si = ni;
            }
        }
        float gr = __shfl_up(sr, 1, 64);
        float gi = __shfl_up(si, 1, 64);
        if (l == 0) { gr = 1.f; gi = 0.f; }
        float s0r = cxr * gr - cxi * gi;
        float s0i = cxr * gi + cxi * gr;
        float s1r = s0r * vr0 - s0i * vi0;
        float s1i = s0r * vi0 + s0i * vr0;
        seed4[((size_t)b * LL + (size_t)i * LQ) / 2 + l] =
            make_float4(s0r, -s0i, s1r, -s1i);
    }
}

// ---------------------------------------------------------------------------
// Layer-2 tap: packed 8x16 real matvec over complex f1 + rotation by link.
__device__ __forceinline__ void l2_tap(const float* __restrict__ w,
                                       const f2 (*__restrict__ f1)[NPTS],
                                       int pos, float lr, float li,
                                       f2* a2) {
    f2 s[O2];
#pragma unroll
    for (int o = 0; o < O2; ++o) s[o] = (f2){0.f, 0.f};
#pragma unroll
    for (int h = 0; h < H1; ++h) {
        f2 f = f1[h][pos];
#pragma unroll
        for (int o = 0; o < O2; ++o) s[o] += w[o * H1 + h] * f;  // v_pk_fma
    }
    f2 rot = (f2){-li, li};
#pragma unroll
    for (int o = 0; o < O2; ++o) {
        f2 sw = (f2){s[o].y, s[o].x};
        a2[o] += lr * s[o] + rot * sw;
    }
}

// ---------------------------------------------------------------------------
// Fused: link-stage -> plaquette pc/pavg -> layer1+modrelu -> layer2 -> out
__global__ __launch_bounds__(256)
void k_main(const float* __restrict__ x,
            const float* __restrict__ c1, const float* __restrict__ fw1,
            const float* __restrict__ bw1, const float* __restrict__ b1,
            const float* __restrict__ c2, const float* __restrict__ fw2,
            const float* __restrict__ bw2, const float* __restrict__ b2,
            const float* __restrict__ ro, const float* __restrict__ rob,
            const float* __restrict__ ws, float* __restrict__ out) {
    __shared__ f2 s_f1[H1][NPTS];     // 41472 B
    __shared__ f2 s_ux[LKN];          // 4232 B
    __shared__ f2 s_uy[LKN];          // 4232 B
    __shared__ float s_pc[PCN];       // 1936 B
    __shared__ float s_pv[PVN];       // 1600 B   (total 53472 B -> 3 blk/CU)
    int tid = threadIdx.x;
    int b = blockIdx.z, i0 = blockIdx.y * TILE, j0 = blockIdx.x * TILE;
    const float* x0 = x + (size_t)b * 4 * LL;
    const float* x1 = x0 + LL;
    const float* x2 = x0 + 2 * LL;
    const float* x3 = x0 + 3 * LL;
    const float2* seed = (const float2*)ws + (size_t)b * LL;

    // ---- Phase A: stage links (23x23, origin i0-3/j0-3) ----
    for (int p = tid; p < LKN; p += 256) {
        int ri = p / LKR, rj = p - ri * LKR;
        int gi = wrapi(i0 - 3 + ri), gj = wrapi(j0 - 3 + rj);
        int idx = gi * LQ + gj;
        s_ux[p] = (f2){x0[idx], x1[idx]};
        s_uy[p] = (f2){x2[idx], x3[idx]};
    }
    __syncthreads();

    // ---- Phase B: pc on 22x22 via complex plaquette product ----
    for (int p = tid; p < PCN; p += 256) {
        int ri = p / PCR, rj = p - ri * PCR;
        int lb = ri * LKR + rj;                 // same origin as links
        f2 u1 = s_ux[lb];                       // ux(i,j)
        f2 u2 = s_uy[lb + LKR];                 // uy(i+1,j)
        f2 u3 = s_ux[lb + 1];                   // ux(i,j+1) (conj below)
        f2 u4 = s_uy[lb];                       // uy(i,j)   (conj below)
        float ar = u1.x * u2.x - u1.y * u2.y, ai = u1.x * u2.y + u1.y * u2.x;
        float br = ar * u3.x + ai * u3.y,     bi = -ar * u3.y + ai * u3.x;
        float zr = br * u4.x + bi * u4.y,     zi = -br * u4.y + bi * u4.x;
        s_pc[p] = zr * __frsqrt_rn(fmaf(zr, zr, zi * zi) + 1e-30f);
    }
    __syncthreads();

    // ---- Phase B2: pavg on 20x20 (origin i0-2) ----
    for (int p = tid; p < PVN; p += 256) {
        int ri = p / PVR, rj = p - ri * PVR;
        int c = (ri + 1) * PCR + (rj + 1);
        s_pv[p] = (s_pc[c] + s_pc[c - PCR] + s_pc[c + PCR]
                 + s_pc[c - 1] + s_pc[c + 1]) * 0.2f;
    }
    __syncthreads();

    // ---- Phase C: layer1 + modrelu on 18x18 -> s_f1 ----
    for (int p = tid; p < NPTS; p += 256) {
        int ri = p / REG, rj = p - ri * REG;
        int di = ri - 1, dj = rj - 1;
        int gi = wrapi(i0 + di), gj = wrapi(j0 + dj);
        int gip = wrapi(gi + 1), gim = wrapi(gi - 1);
        int gjp = wrapi(gj + 1), gjm = wrapi(gj - 1);
        int idc = gi * LQ + gj;
        float2 SC  = seed[idc];
        float2 SXP = seed[gip * LQ + gj];
        float2 SXM = seed[gim * LQ + gj];
        float2 SYP = seed[gi * LQ + gjp];
        float2 SYM = seed[gi * LQ + gjm];
        int llb = (di + 3) * LKR + (dj + 3);
        f2 lx = s_ux[llb], ly = s_uy[llb];
        f2 mxv = s_ux[llb - LKR], myv = s_uy[llb - 1];
        float lxr = lx.x, lxi = lx.y, lyr = ly.x, lyi = ly.y;
        float mxr = mxv.x, mxi = -mxv.y, myr = myv.x, myi = -myv.y;

        int cb = (di + 3) * PCR + (dj + 3);
        int vb = (di + 2) * PVR + (dj + 2);

        f2 t[5]; float tc[5], tv[5];
        t[0] = (f2){SC.x, SC.y};
        tc[0] = s_pc[cb];       tv[0] = s_pv[vb];
        t[1] = (f2){lxr * SXP.x - lxi * SXP.y, lxr * SXP.y + lxi * SXP.x};
        tc[1] = s_pc[cb + PCR]; tv[1] = s_pv[vb + PVR];
        t[2] = (f2){mxr * SXM.x - mxi * SXM.y, mxr * SXM.y + mxi * SXM.x};
        tc[2] = s_pc[cb - PCR]; tv[2] = s_pv[vb - PVR];
        t[3] = (f2){lyr * SYP.x - lyi * SYP.y, lyr * SYP.y + lyi * SYP.x};
        tc[3] = s_pc[cb + 1];   tv[3] = s_pv[vb + 1];
        t[4] = (f2){myr * SYM.x - myi * SYM.y, myr * SYM.y + myi * SYM.x};
        tc[4] = s_pc[cb - 1];   tv[4] = s_pv[vb - 1];

#pragma unroll
        for (int o = 0; o < H1; ++o) {
            float m0 = fmaf(c1[o * 3 + 2], tv[0], fmaf(c1[o * 3 + 1], tc[0], c1[o * 3]));
            float m1 = fmaf(fw1[o * 3 + 2], tv[1], fmaf(fw1[o * 3 + 1], tc[1], fw1[o * 3]));
            float m2 = fmaf(bw1[o * 3 + 2], tv[2], fmaf(bw1[o * 3 + 1], tc[2], bw1[o * 3]));
            float m3 = fmaf(fw1[48 + o * 3 + 2], tv[3], fmaf(fw1[48 + o * 3 + 1], tc[3], fw1[48 + o * 3]));
            float m4 = fmaf(bw1[48 + o * 3 + 2], tv[4], fmaf(bw1[48 + o * 3 + 1], tc[4], bw1[48 + o * 3]));
            f2 acc = t[0] * m0;                 // v_pk_mul / v_pk_fma chain
            acc += t[1] * m1;
            acc += t[2] * m2;
            acc += t[3] * m3;
            acc += t[4] * m4;
            float q = fmaf(acc.x, acc.x, acc.y * acc.y) + 1e-12f;
            float s = fmaxf(fmaf(b1[o], __frsqrt_rn(q), 1.f), 0.f);
            s_f1[o][p] = acc * s;
        }
    }
    __syncthreads();

    // ---- Phase D: layer2 + modrelu + readout ----
    int ty = tid >> 4, tx = tid & 15;
    int i = i0 + ty, j = j0 + tx;
    int llb = (ty + 3) * LKR + (tx + 3);
    f2 lx = s_ux[llb], ly = s_uy[llb];
    f2 mxv = s_ux[llb - LKR], myv = s_uy[llb - 1];
    int pc_ = (ty + 1) * REG + (tx + 1);

    f2 a2[O2];
#pragma unroll
    for (int o = 0; o < O2; ++o) a2[o] = (f2){0.f, 0.f};
    l2_tap(c2,            s_f1, pc_,       1.f,   0.f,    a2);
    l2_tap(fw2,           s_f1, pc_ + REG, lx.x,  lx.y,   a2);
    l2_tap(bw2,           s_f1, pc_ - REG, mxv.x, -mxv.y, a2);
    l2_tap(fw2 + O2 * H1, s_f1, pc_ + 1,   ly.x,  ly.y,   a2);
    l2_tap(bw2 + O2 * H1, s_f1, pc_ - 1,   myv.x, -myv.y, a2);

    float res = rob[0];
#pragma unroll
    for (int o = 0; o < O2; ++o) {
        float q = fmaf(a2[o].x, a2[o].x, a2[o].y * a2[o].y);
        float s = fmaxf(fmaf(b2[o], __frsqrt_rn(q + 1e-12f), 1.f), 0.f);
        res = fmaf(ro[o], s * s * q, res);
    }
    out[(size_t)b * LL + i * LQ + j] = res;
}

// ---------------------------------------------------------------------------
extern "C" void kernel_launch(void* const* d_in, const int* in_sizes, int n_in,
                              void* d_out, int out_size, void* d_ws, size_t ws_size,
                              hipStream_t stream) {
    const float* x   = (const float*)d_in[0];
    const float* c1  = (const float*)d_in[1];
    const float* fw1 = (const float*)d_in[2];
    const float* bw1 = (const float*)d_in[3];
    const float* b1  = (const float*)d_in[4];
    const float* c2  = (const float*)d_in[5];
    const float* fw2 = (const float*)d_in[6];
    const float* bw2 = (const float*)d_in[7];
    const float* b2  = (const float*)d_in[8];
    const float* ro  = (const float*)d_in[9];
    const float* rob = (const float*)d_in[10];
    float* out = (float*)d_out;
    float* ws  = (float*)d_ws;

    k_scan<<<BQ * 8, 256, 0, stream>>>(x, ws);
    dim3 grid(LQ / TILE, LQ / TILE, BQ);
    k_main<<<grid, 256, 0, stream>>>(x, c1, fw1, bw1, b1, c2, fw2, bw2, b2,
                                     ro, rob, ws, out);
}

// Round 6
// 150.649 us; speedup vs baseline: 2.5194x; 1.0973x over previous
//
#include <hip/hip_runtime.h>
#include <math.h>

// B=64, L=128, H=16, O=8
#define LQ   128
#define BQ   64
#define LL   (LQ*LQ)
#define H1   16
#define O2   8
#define TILE 16
#define REG  18          // f1 region (origin i0-1)
#define NPTS (REG*REG)   // 324
#define PCR  22          // pc region (origin i0-3)
#define PCN  (PCR*PCR)   // 484
#define LKR  23          // link region (origin i0-3)
#define LKN  (LKR*LKR)   // 529
#define SDR  20          // seed tile (origin i0-2)
#define SDN  (SDR*SDR)   // 400
#define FSTR 20          // f1 point stride in dwords (16 data + 4 pad, 80 B)

typedef float f2 __attribute__((ext_vector_type(2)));

__device__ __forceinline__ int wrapi(int v) { return v & (LQ - 1); }

// round-to-nearest-even f32 -> bf16 (returned in low 16 bits)
__device__ __forceinline__ unsigned f2bf(float f) {
    unsigned u = __float_as_uint(f);
    u += 0x7fffu + ((u >> 16) & 1u);
    return u >> 16;
}

// ws layout:
//   float2[0 .. BQ*LL)          seed (8 MB)
//   float2[BQ*LL .. BQ*LL+120)  repacked layer-1 weights W1[t][c][op] (960 B)
#define WS_W1 ((size_t)BQ * LL)

// ---------------------------------------------------------------------------
// Fused x-scan + row scans (+ one extra block repacks layer-1 weights).
__global__ __launch_bounds__(256)
void k_scan(const float* __restrict__ x,
            const float* __restrict__ c1, const float* __restrict__ fw1,
            const float* __restrict__ bw1, float* __restrict__ ws) {
    int blk = blockIdx.x;
    if (blk == BQ * 8) {
        // weight repack: W1[t][c][op] = (w_t[2op][c], w_t[2op+1][c])
        int tid = threadIdx.x;
        if (tid < 120) {
            int t = tid / 24, r = tid - t * 24;
            int c = r >> 3, op = r & 7;
            const float* src = (t == 0) ? c1 : (t == 1) ? fw1 : (t == 2) ? bw1
                             : (t == 3) ? (fw1 + 48) : (bw1 + 48);
            float2 v = make_float2(src[(2 * op) * 3 + c], src[(2 * op + 1) * 3 + c]);
            ((float2*)ws)[WS_W1 + tid] = v;
        }
        return;
    }
    int b = blk >> 3, rq = blk & 7;
    int l = threadIdx.x & 63, w = threadIdx.x >> 6;
    const float* x0 = x + (size_t)b * 4 * LL;
    const float* x1 = x0 + LL;

    float ur0 = x0[(2 * l) * LQ],     ui0 = x1[(2 * l) * LQ];
    float ur1 = x0[(2 * l + 1) * LQ], ui1 = x1[(2 * l + 1) * LQ];
    float pr = ur0 * ur1 - ui0 * ui1;
    float pi = ur0 * ui1 + ui0 * ur1;
    for (int d = 1; d < 64; d <<= 1) {
        float qr = __shfl_up(pr, d, 64);
        float qi = __shfl_up(pi, d, 64);
        if (l >= d) {
            float nr = qr * pr - qi * pi;
            float ni = qr * pi + qi * pr;
            pr = nr; pi = ni;
        }
    }
    float er = __shfl_up(pr, 1, 64);
    float ei = __shfl_up(pi, 1, 64);
    if (l == 0) { er = 1.f; ei = 0.f; }
    float e1r = er * ur0 - ei * ui0;
    float e1i = er * ui0 + ei * ur0;

    const float* yrp = x + (size_t)(b * 4 + 2) * LL;
    const float* yip = yrp + LL;
    float4* seed4 = (float4*)ws;

    for (int k = 0; k < 4; ++k) {
        int i = rq * 16 + w * 4 + k;
        float cxr = __shfl((i & 1) ? e1r : er, i >> 1, 64);
        float cxi = __shfl((i & 1) ? e1i : ei, i >> 1, 64);
        const float* yr = yrp + (size_t)i * LQ;
        const float* yi = yip + (size_t)i * LQ;
        float vr0 = yr[2 * l],     vi0 = yi[2 * l];
        float vr1 = yr[2 * l + 1], vi1 = yi[2 * l + 1];
        float sr = vr0 * vr1 - vi0 * vi1;
        float si = vr0 * vi1 + vi0 * vr1;
        for (int d = 1; d < 64; d <<= 1) {
            float qr = __shfl_up(sr, d, 64);
            float qi = __shfl_up(si, d, 64);
            if (l >= d) {
                float nr = qr * sr - qi * si;
                float ni = qr * si + qi * sr;
                sr = nr; si = ni;
            }
        }
        float gr = __shfl_up(sr, 1, 64);
        float gi = __shfl_up(si, 1, 64);
        if (l == 0) { gr = 1.f; gi = 0.f; }
        float s0r = cxr * gr - cxi * gi;
        float s0i = cxr * gi + cxi * gr;
        float s1r = s0r * vr0 - s0i * vi0;
        float s1i = s0r * vi0 + s0i * vr0;
        seed4[((size_t)b * LL + (size_t)i * LQ) / 2 + l] =
            make_float4(s0r, -s0i, s1r, -s1i);
    }
}

// ---------------------------------------------------------------------------
// Fused main kernel.
__global__ __launch_bounds__(256, 4)
void k_main(const float* __restrict__ x,
            const float* __restrict__ c2, const float* __restrict__ fw2,
            const float* __restrict__ bw2, const float* __restrict__ b1,
            const float* __restrict__ b2,
            const float* __restrict__ ro, const float* __restrict__ rob,
            const float* __restrict__ ws, float* __restrict__ out) {
    __shared__ unsigned s_f1[NPTS * FSTR];  // bf16 complex, point-major: 25920 B
    __shared__ f2 s_ux[LKN];                // 4232 B
    __shared__ f2 s_uy[LKN];                // 4232 B
    __shared__ float s_pc[PCN];             // 1936 B
    __shared__ f2 s_sd[SDN];                // 3200 B   total 39520 B -> 4 blk/CU
    int tid = threadIdx.x;
    int b = blockIdx.z, i0 = blockIdx.y * TILE, j0 = blockIdx.x * TILE;
    const float* x0 = x + (size_t)b * 4 * LL;
    const float* x1 = x0 + LL;
    const float* x2 = x0 + 2 * LL;
    const float* x3 = x0 + 3 * LL;
    const float2* seed = (const float2*)ws + (size_t)b * LL;
    const float2* W1 = (const float2*)ws + WS_W1;   // [t][c][op]

    // ---- Phase A: stage links (23x23, origin -3) + seed (20x20, origin -2) ----
    for (int p = tid; p < LKN; p += 256) {
        int ri = p / LKR, rj = p - ri * LKR;
        int gi = wrapi(i0 - 3 + ri), gj = wrapi(j0 - 3 + rj);
        int idx = gi * LQ + gj;
        s_ux[p] = (f2){x0[idx], x1[idx]};
        s_uy[p] = (f2){x2[idx], x3[idx]};
    }
    for (int p = tid; p < SDN; p += 256) {
        int ri = p / SDR, rj = p - ri * SDR;
        int gi = wrapi(i0 - 2 + ri), gj = wrapi(j0 - 2 + rj);
        float2 s = seed[gi * LQ + gj];
        s_sd[p] = (f2){s.x, s.y};
    }
    __syncthreads();

    // ---- Phase B: pc on 22x22 (origin -3) via complex plaquette product ----
    for (int p = tid; p < PCN; p += 256) {
        int ri = p / PCR, rj = p - ri * PCR;
        int lb = ri * LKR + rj;
        f2 u1 = s_ux[lb];
        f2 u2 = s_uy[lb + LKR];
        f2 u3 = s_ux[lb + 1];
        f2 u4 = s_uy[lb];
        float ar = u1.x * u2.x - u1.y * u2.y, ai = u1.x * u2.y + u1.y * u2.x;
        float br = ar * u3.x + ai * u3.y,     bi = -ar * u3.y + ai * u3.x;
        float zr = br * u4.x + bi * u4.y,     zi = -br * u4.y + bi * u4.x;
        s_pc[p] = zr * __frsqrt_rn(fmaf(zr, zr, zi * zi) + 1e-30f);
    }
    __syncthreads();

    // ---- Phase C: layer1 + modrelu on 18x18 -> bf16 point-major LDS ----
#pragma unroll
    for (int pass = 0; pass < 2; ++pass) {
        int p = tid + pass * 256;
        if (pass == 1 && p >= NPTS) break;
        int ri = p / REG, rj = p - ri * REG;
        int sc = (ri + 1) * SDR + (rj + 1);     // seed center (origin -2)
        int lb = (ri + 2) * LKR + (rj + 2);     // link center (origin -3)
        int cb = (ri + 2) * PCR + (rj + 2);     // pc center   (origin -3)

        f2 t[5]; float tc[5], tv[5];
        {
            f2 SC = s_sd[sc], SXP = s_sd[sc + SDR], SXM = s_sd[sc - SDR];
            f2 SYP = s_sd[sc + 1], SYM = s_sd[sc - 1];
            f2 lx = s_ux[lb], ly = s_uy[lb];
            f2 mx = s_ux[lb - LKR], my = s_uy[lb - 1];
            t[0] = SC;
            t[1] = (f2){lx.x * SXP.x - lx.y * SXP.y, lx.x * SXP.y + lx.y * SXP.x};
            t[2] = (f2){mx.x * SXM.x + mx.y * SXM.y, mx.x * SXM.y - mx.y * SXM.x};
            t[3] = (f2){ly.x * SYP.x - ly.y * SYP.y, ly.x * SYP.y + ly.y * SYP.x};
            t[4] = (f2){my.x * SYM.x + my.y * SYM.y, my.x * SYM.y - my.y * SYM.x};
            int ct[5] = {cb, cb + PCR, cb - PCR, cb + 1, cb - 1};
#pragma unroll
            for (int q = 0; q < 5; ++q) {
                int c = ct[q];
                tc[q] = s_pc[c];
                tv[q] = (s_pc[c] + s_pc[c - PCR] + s_pc[c + PCR]
                       + s_pc[c - 1] + s_pc[c + 1]) * 0.2f;
            }
        }

        f2 accr[8], acci[8];
#pragma unroll
        for (int op = 0; op < 8; ++op) { accr[op] = (f2){0.f, 0.f}; acci[op] = (f2){0.f, 0.f}; }
#pragma unroll
        for (int q = 0; q < 5; ++q) {
            f2 tcv = (f2){tc[q], tc[q]}, tvv = (f2){tv[q], tv[q]};
            f2 trv = (f2){t[q].x, t[q].x}, tiv = (f2){t[q].y, t[q].y};
            const float2* Wq = W1 + q * 24;
#pragma unroll
            for (int op = 0; op < 8; ++op) {
                float2 w0 = Wq[op], w1 = Wq[8 + op], w2 = Wq[16 + op];
                f2 mp = (f2){w0.x, w0.y};
                mp += (f2){w1.x, w1.y} * tcv;       // v_pk_fma
                mp += (f2){w2.x, w2.y} * tvv;
                accr[op] += mp * trv;
                acci[op] += mp * tiv;
            }
        }
        // modrelu1 + bf16 pack (point-major, stride FSTR dwords)
        unsigned* fp = &s_f1[p * FSTR];
#pragma unroll
        for (int op = 0; op < 8; ++op) {
            f2 q2 = accr[op] * accr[op] + acci[op] * acci[op] + (f2){1e-12f, 1e-12f};
            float s0 = fmaxf(fmaf(b1[2 * op],     __frsqrt_rn(q2.x), 1.f), 0.f);
            float s1 = fmaxf(fmaf(b1[2 * op + 1], __frsqrt_rn(q2.y), 1.f), 0.f);
            f2 sv = (f2){s0, s1};
            f2 fr = accr[op] * sv, fi = acci[op] * sv;
            // pack (r,i) bf16 pairs: low = r, high = i
            unsigned u0 = f2bf(fr.x) | (f2bf(fi.x) << 16);
            unsigned u1 = f2bf(fr.y) | (f2bf(fi.y) << 16);
            *(uint2*)&fp[2 * op] = make_uint2(u0, u1);   // h=2op, 2op+1
        }
    }
    __syncthreads();

    // ---- Phase D: layer2 + modrelu + readout ----
    int ty = tid >> 4, tx = tid & 15;
    int i = i0 + ty, j = j0 + tx;
    int pos = (ty + 1) * REG + (tx + 1);
    int lb2 = (ty + 3) * LKR + (tx + 3);
    f2 lx = s_ux[lb2], ly = s_uy[lb2];
    f2 mx = s_ux[lb2 - LKR], my = s_uy[lb2 - 1];

    f2 a2[O2];
#pragma unroll
    for (int o = 0; o < O2; ++o) a2[o] = (f2){0.f, 0.f};

    const float* wt[5] = {c2, fw2, bw2, fw2 + O2 * H1, bw2 + O2 * H1};
    int   dp[5] = {0, REG, -REG, 1, -1};
    float lr[5] = {1.f, lx.x, mx.x,  ly.x, my.x};
    float li[5] = {0.f, lx.y, -mx.y, ly.y, -my.y};

#pragma unroll
    for (int q = 0; q < 5; ++q) {
        const unsigned* fp = &s_f1[(pos + dp[q]) * FSTR];
        unsigned dw[16];
#pragma unroll
        for (int k = 0; k < 4; ++k)
            *(uint4*)&dw[4 * k] = *(const uint4*)&fp[4 * k];   // ds_read_b128
        const float* w = wt[q];
        f2 s[O2];
#pragma unroll
        for (int o = 0; o < O2; ++o) s[o] = (f2){0.f, 0.f};
#pragma unroll
        for (int h = 0; h < H1; ++h) {
            f2 f = (f2){__uint_as_float(dw[h] << 16),
                        __uint_as_float(dw[h] & 0xffff0000u)};
#pragma unroll
            for (int o = 0; o < O2; ++o) s[o] += w[o * H1 + h] * f;  // v_pk_fma
        }
        f2 rot = (f2){-li[q], li[q]};
#pragma unroll
        for (int o = 0; o < O2; ++o) {
            f2 sw = (f2){s[o].y, s[o].x};
            a2[o] += lr[q] * s[o] + rot * sw;
        }
    }

    float res = rob[0];
#pragma unroll
    for (int o = 0; o < O2; ++o) {
        float q = fmaf(a2[o].x, a2[o].x, a2[o].y * a2[o].y);
        float s = fmaxf(fmaf(b2[o], __frsqrt_rn(q + 1e-12f), 1.f), 0.f);
        res = fmaf(ro[o], s * s * q, res);
    }
    out[(size_t)b * LL + i * LQ + j] = res;
}

// ---------------------------------------------------------------------------
extern "C" void kernel_launch(void* const* d_in, const int* in_sizes, int n_in,
                              void* d_out, int out_size, void* d_ws, size_t ws_size,
                              hipStream_t stream) {
    const float* x   = (const float*)d_in[0];
    const float* c1  = (const float*)d_in[1];
    const float* fw1 = (const float*)d_in[2];
    const float* bw1 = (const float*)d_in[3];
    const float* b1  = (const float*)d_in[4];
    const float* c2  = (const float*)d_in[5];
    const float* fw2 = (const float*)d_in[6];
    const float* bw2 = (const float*)d_in[7];
    const float* b2  = (const float*)d_in[8];
    const float* ro  = (const float*)d_in[9];
    const float* rob = (const float*)d_in[10];
    float* out = (float*)d_out;
    float* ws  = (float*)d_ws;

    k_scan<<<BQ * 8 + 1, 256, 0, stream>>>(x, c1, fw1, bw1, ws);
    dim3 grid(LQ / TILE, LQ / TILE, BQ);
    k_main<<<grid, 256, 0, stream>>>(x, c2, fw2, bw2, b1, b2,
                                     ro, rob, ws, out);
}

// Round 7
// 145.403 us; speedup vs baseline: 2.6103x; 1.0361x over previous
//
#include <hip/hip_runtime.h>
#include <math.h>

// B=64, L=128, H=16, O=8
#define LQ   128
#define BQ   64
#define LL   (LQ*LQ)
#define H1   16
#define O2   8
#define TILE 16
#define REG  18          // f1 region (origin i0-1)
#define NPTS (REG*REG)   // 324
#define PCR  22          // pc region (origin i0-3)
#define PCN  (PCR*PCR)   // 484
#define LKR  23          // link region (origin i0-3)
#define LKN  (LKR*LKR)   // 529
#define SDR  20          // seed tile (origin i0-2)
#define SDN  (SDR*SDR)   // 400
#define FSTR 10          // f1 plane stride per point in dwords (8 data + 2 pad)

typedef float f2 __attribute__((ext_vector_type(2)));
using bf8 = __attribute__((ext_vector_type(8))) short;   // 8 bf16 (4 VGPR)
using f4  = __attribute__((ext_vector_type(4))) float;   // MFMA C/D

__device__ __forceinline__ int wrapi(int v) { return v & (LQ - 1); }

// round-to-nearest-even f32 -> bf16 (low 16 bits)
__device__ __forceinline__ unsigned f2bf(float f) {
    unsigned u = __float_as_uint(f);
    u += 0x7fffu + ((u >> 16) & 1u);
    return u >> 16;
}

// ws layout:
//   float2[0 .. BQ*LL)          seed (8 MB)
//   float2[BQ*LL .. BQ*LL+120)  repacked layer-1 weights W1[t][c][op]
#define WS_W1 ((size_t)BQ * LL)

// ---------------------------------------------------------------------------
__global__ __launch_bounds__(256)
void k_scan(const float* __restrict__ x,
            const float* __restrict__ c1, const float* __restrict__ fw1,
            const float* __restrict__ bw1, float* __restrict__ ws) {
    int blk = blockIdx.x;
    if (blk == BQ * 8) {
        int tid = threadIdx.x;
        if (tid < 120) {
            int t = tid / 24, r = tid - t * 24;
            int c = r >> 3, op = r & 7;
            const float* src = (t == 0) ? c1 : (t == 1) ? fw1 : (t == 2) ? bw1
                             : (t == 3) ? (fw1 + 48) : (bw1 + 48);
            float2 v = make_float2(src[(2 * op) * 3 + c], src[(2 * op + 1) * 3 + c]);
            ((float2*)ws)[WS_W1 + tid] = v;
        }
        return;
    }
    int b = blk >> 3, rq = blk & 7;
    int l = threadIdx.x & 63, w = threadIdx.x >> 6;
    const float* x0 = x + (size_t)b * 4 * LL;
    const float* x1 = x0 + LL;

    float ur0 = x0[(2 * l) * LQ],     ui0 = x1[(2 * l) * LQ];
    float ur1 = x0[(2 * l + 1) * LQ], ui1 = x1[(2 * l + 1) * LQ];
    float pr = ur0 * ur1 - ui0 * ui1;
    float pi = ur0 * ui1 + ui0 * ur1;
    for (int d = 1; d < 64; d <<= 1) {
        float qr = __shfl_up(pr, d, 64);
        float qi = __shfl_up(pi, d, 64);
        if (l >= d) {
            float nr = qr * pr - qi * pi;
            float ni = qr * pi + qi * pr;
            pr = nr; pi = ni;
        }
    }
    float er = __shfl_up(pr, 1, 64);
    float ei = __shfl_up(pi, 1, 64);
    if (l == 0) { er = 1.f; ei = 0.f; }
    float e1r = er * ur0 - ei * ui0;
    float e1i = er * ui0 + ei * ur0;

    const float* yrp = x + (size_t)(b * 4 + 2) * LL;
    const float* yip = yrp + LL;
    float4* seed4 = (float4*)ws;

    for (int k = 0; k < 4; ++k) {
        int i = rq * 16 + w * 4 + k;
        float cxr = __shfl((i & 1) ? e1r : er, i >> 1, 64);
        float cxi = __shfl((i & 1) ? e1i : ei, i >> 1, 64);
        const float* yr = yrp + (size_t)i * LQ;
        const float* yi = yip + (size_t)i * LQ;
        float vr0 = yr[2 * l],     vi0 = yi[2 * l];
        float vr1 = yr[2 * l + 1], vi1 = yi[2 * l + 1];
        float sr = vr0 * vr1 - vi0 * vi1;
        float si = vr0 * vi1 + vi0 * vr1;
        for (int d = 1; d < 64; d <<= 1) {
            float qr = __shfl_up(sr, d, 64);
            float qi = __shfl_up(si, d, 64);
            if (l >= d) {
                float nr = qr * sr - qi * si;
                float ni = qr * si + qi * sr;
                sr = nr; si = ni;
            }
        }
        float gr = __shfl_up(sr, 1, 64);
        float gi = __shfl_up(si, 1, 64);
        if (l == 0) { gr = 1.f; gi = 0.f; }
        float s0r = cxr * gr - cxi * gi;
        float s0i = cxr * gi + cxi * gr;
        float s1r = s0r * vr0 - s0i * vi0;
        float s1i = s0r * vi0 + s0i * vr0;
        seed4[((size_t)b * LL + (size_t)i * LQ) / 2 + l] =
            make_float4(s0r, -s0i, s1r, -s1i);
    }
}

// ---------------------------------------------------------------------------
__global__ __launch_bounds__(256, 4)
void k_main(const float* __restrict__ x,
            const float* __restrict__ c2, const float* __restrict__ fw2,
            const float* __restrict__ bw2, const float* __restrict__ b1,
            const float* __restrict__ b2,
            const float* __restrict__ ro, const float* __restrict__ rob,
            const float* __restrict__ ws, float* __restrict__ out) {
    __shared__ unsigned s_f1r[NPTS * FSTR];  // bf16 pairs, h-major: 12960 B
    __shared__ unsigned s_f1i[NPTS * FSTR];  // 12960 B
    __shared__ f2 s_ux[LKN];                 // 4232 B
    __shared__ f2 s_uy[LKN];                 // 4232 B
    __shared__ float s_pc[PCN];              // 1936 B
    __shared__ f2 s_sd[SDN];                 // 3200 B  (total 39520 -> 4 blk/CU)
    int tid = threadIdx.x;
    int b = blockIdx.z, i0 = blockIdx.y * TILE, j0 = blockIdx.x * TILE;
    const float* x0 = x + (size_t)b * 4 * LL;
    const float* x1 = x0 + LL;
    const float* x2 = x0 + 2 * LL;
    const float* x3 = x0 + 3 * LL;
    const float2* seed = (const float2*)ws + (size_t)b * LL;
    const float2* W1 = (const float2*)ws + WS_W1;

    // uniform zero-bias fast-path flags (exact: scale==1.0 when bias==0)
    bool z1 = true;
#pragma unroll
    for (int h = 0; h < H1; ++h) z1 = z1 && (b1[h] == 0.f);
    bool z2 = true;
#pragma unroll
    for (int o = 0; o < O2; ++o) z2 = z2 && (b2[o] == 0.f);

    // ---- Phase A: stage links (23x23, origin -3) + seed (20x20, origin -2) ----
    for (int p = tid; p < LKN; p += 256) {
        int ri = p / LKR, rj = p - ri * LKR;
        int gi = wrapi(i0 - 3 + ri), gj = wrapi(j0 - 3 + rj);
        int idx = gi * LQ + gj;
        s_ux[p] = (f2){x0[idx], x1[idx]};
        s_uy[p] = (f2){x2[idx], x3[idx]};
    }
    for (int p = tid; p < SDN; p += 256) {
        int ri = p / SDR, rj = p - ri * SDR;
        int gi = wrapi(i0 - 2 + ri), gj = wrapi(j0 - 2 + rj);
        float2 s = seed[gi * LQ + gj];
        s_sd[p] = (f2){s.x, s.y};
    }
    __syncthreads();

    // ---- Phase B: pc on 22x22 (origin -3) via complex plaquette product ----
    for (int p = tid; p < PCN; p += 256) {
        int ri = p / PCR, rj = p - ri * PCR;
        int lb = ri * LKR + rj;
        f2 u1 = s_ux[lb];
        f2 u2 = s_uy[lb + LKR];
        f2 u3 = s_ux[lb + 1];
        f2 u4 = s_uy[lb];
        float ar = u1.x * u2.x - u1.y * u2.y, ai = u1.x * u2.y + u1.y * u2.x;
        float br = ar * u3.x + ai * u3.y,     bi = -ar * u3.y + ai * u3.x;
        float zr = br * u4.x + bi * u4.y,     zi = -br * u4.y + bi * u4.x;
        s_pc[p] = zr * __frsqrt_rn(fmaf(zr, zr, zi * zi) + 1e-30f);
    }
    __syncthreads();

    // ---- Phase C: layer1 (+modrelu) on 18x18 -> split bf16 h-major planes ----
#pragma unroll
    for (int pass = 0; pass < 2; ++pass) {
        int p = tid + pass * 256;
        if (pass == 1 && p >= NPTS) break;
        int ri = p / REG, rj = p - ri * REG;
        int sc = (ri + 1) * SDR + (rj + 1);
        int lb = (ri + 2) * LKR + (rj + 2);
        int cb = (ri + 2) * PCR + (rj + 2);

        f2 t[5]; float tc[5], tv[5];
        {
            f2 SC = s_sd[sc], SXP = s_sd[sc + SDR], SXM = s_sd[sc - SDR];
            f2 SYP = s_sd[sc + 1], SYM = s_sd[sc - 1];
            f2 lx = s_ux[lb], ly = s_uy[lb];
            f2 mx = s_ux[lb - LKR], my = s_uy[lb - 1];
            t[0] = SC;
            t[1] = (f2){lx.x * SXP.x - lx.y * SXP.y, lx.x * SXP.y + lx.y * SXP.x};
            t[2] = (f2){mx.x * SXM.x + mx.y * SXM.y, mx.x * SXM.y - mx.y * SXM.x};
            t[3] = (f2){ly.x * SYP.x - ly.y * SYP.y, ly.x * SYP.y + ly.y * SYP.x};
            t[4] = (f2){my.x * SYM.x + my.y * SYM.y, my.x * SYM.y - my.y * SYM.x};
            int ct[5] = {cb, cb + PCR, cb - PCR, cb + 1, cb - 1};
#pragma unroll
            for (int q = 0; q < 5; ++q) {
                int c = ct[q];
                tc[q] = s_pc[c];
                tv[q] = (s_pc[c] + s_pc[c - PCR] + s_pc[c + PCR]
                       + s_pc[c - 1] + s_pc[c + 1]) * 0.2f;
            }
        }

        f2 accr[8], acci[8];
#pragma unroll
        for (int op = 0; op < 8; ++op) { accr[op] = (f2){0.f, 0.f}; acci[op] = (f2){0.f, 0.f}; }
#pragma unroll
        for (int q = 0; q < 5; ++q) {
            f2 tcv = (f2){tc[q], tc[q]}, tvv = (f2){tv[q], tv[q]};
            f2 trv = (f2){t[q].x, t[q].x}, tiv = (f2){t[q].y, t[q].y};
            const float2* Wq = W1 + q * 24;
#pragma unroll
            for (int op = 0; op < 8; ++op) {
                float2 w0 = Wq[op], w1 = Wq[8 + op], w2 = Wq[16 + op];
                f2 mp = (f2){w0.x, w0.y};
                mp += (f2){w1.x, w1.y} * tcv;
                mp += (f2){w2.x, w2.y} * tvv;
                accr[op] += mp * trv;
                acci[op] += mp * tiv;
            }
        }
        if (!z1) {
#pragma unroll
            for (int op = 0; op < 8; ++op) {
                f2 q2 = accr[op] * accr[op] + acci[op] * acci[op] + (f2){1e-12f, 1e-12f};
                float s0 = fmaxf(fmaf(b1[2 * op],     __frsqrt_rn(q2.x), 1.f), 0.f);
                float s1 = fmaxf(fmaf(b1[2 * op + 1], __frsqrt_rn(q2.y), 1.f), 0.f);
                f2 sv = (f2){s0, s1};
                accr[op] *= sv; acci[op] *= sv;
            }
        }
        // pack: plane dword d holds (h=2d, h=2d+1)
        unsigned* fr_ = &s_f1r[p * FSTR];
        unsigned* fi_ = &s_f1i[p * FSTR];
#pragma unroll
        for (int d = 0; d < 4; ++d) {
            unsigned r0 = f2bf(accr[2*d].x)   | (f2bf(accr[2*d].y) << 16);
            unsigned r1 = f2bf(accr[2*d+1].x) | (f2bf(accr[2*d+1].y) << 16);
            unsigned i0_ = f2bf(acci[2*d].x)   | (f2bf(acci[2*d].y) << 16);
            unsigned i1_ = f2bf(acci[2*d+1].x) | (f2bf(acci[2*d+1].y) << 16);
            *(uint2*)&fr_[2*d] = make_uint2(r0, r1);
            *(uint2*)&fi_[2*d] = make_uint2(i0_, i1_);
        }
    }
    __syncthreads();

    // ---- Phase D: layer2 via MFMA (K=16 real + 16 zero-pad) + readout ----
    int lane = tid & 63, w = tid >> 6;
    int quad = lane >> 4, nIdx = lane & 15;

    // A fragments: A[m=o][k=h] = W_q[o][h], rows 8-15 & k>=16 zero
    const float* wt0 = c2;
    const float* wt1 = fw2;
    const float* wt2 = bw2;
    const float* wt3 = fw2 + O2 * H1;
    const float* wt4 = bw2 + O2 * H1;
    const float* wts[5] = {wt0, wt1, wt2, wt3, wt4};
    bf8 afr[5];
    bool aval = (nIdx < O2) && (quad < 2);
#pragma unroll
    for (int q = 0; q < 5; ++q) {
        bf8 z = {0, 0, 0, 0, 0, 0, 0, 0};
        if (aval) {
            const float* wp = wts[q] + nIdx * H1 + quad * 8;
            float4 wa = *(const float4*)wp;
            float4 wb = *(const float4*)(wp + 4);
            uint4 u;
            u.x = f2bf(wa.x) | (f2bf(wa.y) << 16);
            u.y = f2bf(wa.z) | (f2bf(wa.w) << 16);
            u.z = f2bf(wb.x) | (f2bf(wb.y) << 16);
            u.w = f2bf(wb.z) | (f2bf(wb.w) << 16);
            __builtin_memcpy(&z, &u, 16);
        }
        afr[q] = z;
    }
    float4 ro_lo = *(const float4*)ro;
    float4 ro_hi = *(const float4*)(ro + 4);
    float4 b2_lo = *(const float4*)b2;
    float4 b2_hi = *(const float4*)(b2 + 4);
    float4 zf4 = make_float4(0.f, 0.f, 0.f, 0.f);
    float4 rv = (quad == 0) ? ro_lo : ((quad == 1) ? ro_hi : zf4);
    float4 bv = (quad == 0) ? b2_lo : ((quad == 1) ? b2_hi : zf4);
    float rob0 = rob[0];
    const int dp5[5] = {0, REG, -REG, 1, -1};

    for (int g = 0; g < 4; ++g) {
        int row = w * 4 + g;
        int posc = (row + 1) * REG + (nIdx + 1);
        int lb2 = (row + 3) * LKR + (nIdx + 3);
        f2 lx = s_ux[lb2], ly = s_uy[lb2];
        f2 mx = s_ux[lb2 - LKR], my = s_uy[lb2 - 1];
        float lrq[5] = {1.f, lx.x, mx.x,  ly.x, my.x};
        float liq[5] = {0.f, lx.y, -mx.y, ly.y, -my.y};

        f4 a2r = {0.f, 0.f, 0.f, 0.f}, a2i = {0.f, 0.f, 0.f, 0.f};
#pragma unroll
        for (int q = 0; q < 5; ++q) {
            bf8 br = {0, 0, 0, 0, 0, 0, 0, 0};
            bf8 bi = {0, 0, 0, 0, 0, 0, 0, 0};
            if (quad < 2) {
                int posq = posc + dp5[q];
                const unsigned* pr_ = &s_f1r[posq * FSTR + quad * 4];
                uint2 lo = *(const uint2*)pr_;
                uint2 hi = *(const uint2*)(pr_ + 2);
                uint4 ur = {lo.x, lo.y, hi.x, hi.y};
                __builtin_memcpy(&br, &ur, 16);
                const unsigned* pi_ = &s_f1i[posq * FSTR + quad * 4];
                uint2 lo2 = *(const uint2*)pi_;
                uint2 hi2 = *(const uint2*)(pi_ + 2);
                uint4 ui = {lo2.x, lo2.y, hi2.x, hi2.y};
                __builtin_memcpy(&bi, &ui, 16);
            }
            f4 zc = {0.f, 0.f, 0.f, 0.f};
            f4 sr = __builtin_amdgcn_mfma_f32_16x16x32_bf16(afr[q], br, zc, 0, 0, 0);
            f4 si = __builtin_amdgcn_mfma_f32_16x16x32_bf16(afr[q], bi, zc, 0, 0, 0);
            a2r += lrq[q] * sr - liq[q] * si;
            a2i += lrq[q] * si + liq[q] * sr;
        }

        // epilogue: (modrelu2) + readout, lane holds o = quad*4+reg, pt = nIdx
        f4 q4 = a2r * a2r + a2i * a2i;
        float res;
        if (z2) {
            res = rv.x * q4.x + rv.y * q4.y + rv.z * q4.z + rv.w * q4.w;
        } else {
            float bvv[4] = {bv.x, bv.y, bv.z, bv.w};
            float rvv[4] = {rv.x, rv.y, rv.z, rv.w};
            res = 0.f;
#pragma unroll
            for (int r = 0; r < 4; ++r) {
                float qq = q4[r];
                float s = fmaxf(fmaf(bvv[r], __frsqrt_rn(qq + 1e-12f), 1.f), 0.f);
                res = fmaf(rvv[r], s * s * qq, res);
            }
        }
        res += __shfl_xor(res, 16, 64);
        res += __shfl_xor(res, 32, 64);
        if (quad == 0)
            out[(size_t)b * LL + (size_t)(i0 + row) * LQ + (j0 + nIdx)] = res + rob0;
    }
}

// ---------------------------------------------------------------------------
extern "C" void kernel_launch(void* const* d_in, const int* in_sizes, int n_in,
                              void* d_out, int out_size, void* d_ws, size_t ws_size,
                              hipStream_t stream) {
    const float* x   = (const float*)d_in[0];
    const float* c1  = (const float*)d_in[1];
    const float* fw1 = (const float*)d_in[2];
    const float* bw1 = (const float*)d_in[3];
    const float* b1  = (const float*)d_in[4];
    const float* c2  = (const float*)d_in[5];
    const float* fw2 = (const float*)d_in[6];
    const float* bw2 = (const float*)d_in[7];
    const float* b2  = (const float*)d_in[8];
    const float* ro  = (const float*)d_in[9];
    const float* rob = (const float*)d_in[10];
    float* out = (float*)d_out;
    float* ws  = (float*)d_ws;

    k_scan<<<BQ * 8 + 1, 256, 0, stream>>>(x, c1, fw1, bw1, ws);
    dim3 grid(LQ / TILE, LQ / TILE, BQ);
    k_main<<<grid, 256, 0, stream>>>(x, c2, fw2, bw2, b1, b2,
                                     ro, rob, ws, out);
}

// Round 8
// 134.278 us; speedup vs baseline: 2.8266x; 1.0828x over previous
//
#include <hip/hip_runtime.h>
#include <math.h>

// B=64, L=128, H=16, O=8
#define LQ   128
#define BQ   64
#define LL   (LQ*LQ)
#define H1   16
#define O2   8
#define TILE 16
#define REG  18          // f1 region (origin i0-1)
#define NPTS (REG*REG)   // 324
#define PCR  22          // pc region (origin i0-3)
#define PCN  (PCR*PCR)   // 484
#define LKR  23          // link region (origin i0-3)
#define LKN  (LKR*LKR)   // 529
#define SDR  20          // seed tile (origin i0-2)
#define SDN  (SDR*SDR)   // 400
#define FSTR 10          // f1 plane stride per point in dwords (8 data + 2 pad)

typedef float f2 __attribute__((ext_vector_type(2)));
using bf8 = __attribute__((ext_vector_type(8))) short;   // 8 bf16 (4 VGPR)
using f4  = __attribute__((ext_vector_type(4))) float;   // MFMA C/D

__device__ __forceinline__ int wrapi(int v) { return v & (LQ - 1); }

// pack two f32 -> dword of two bf16 (truncation) : low16=bf(lo), high16=bf(hi)
__device__ __forceinline__ unsigned pack_bf(float hi, float lo) {
    return __builtin_amdgcn_perm(__float_as_uint(hi), __float_as_uint(lo),
                                 0x07060302u);
}

// ws layout:
//   float2[0 .. BQ*LL)          seed (8 MB)
//   float2[BQ*LL .. BQ*LL+120)  repacked layer-1 weights W1[t][c][op]
#define WS_W1 ((size_t)BQ * LL)

// ---------------------------------------------------------------------------
__global__ __launch_bounds__(256)
void k_scan(const float* __restrict__ x,
            const float* __restrict__ c1, const float* __restrict__ fw1,
            const float* __restrict__ bw1, float* __restrict__ ws) {
    int blk = blockIdx.x;
    if (blk == BQ * 8) {
        int tid = threadIdx.x;
        if (tid < 120) {
            int t = tid / 24, r = tid - t * 24;
            int c = r >> 3, op = r & 7;
            const float* src = (t == 0) ? c1 : (t == 1) ? fw1 : (t == 2) ? bw1
                             : (t == 3) ? (fw1 + 48) : (bw1 + 48);
            float2 v = make_float2(src[(2 * op) * 3 + c], src[(2 * op + 1) * 3 + c]);
            ((float2*)ws)[WS_W1 + tid] = v;
        }
        return;
    }
    int b = blk >> 3, rq = blk & 7;
    int l = threadIdx.x & 63, w = threadIdx.x >> 6;
    const float* x0 = x + (size_t)b * 4 * LL;
    const float* x1 = x0 + LL;

    float ur0 = x0[(2 * l) * LQ],     ui0 = x1[(2 * l) * LQ];
    float ur1 = x0[(2 * l + 1) * LQ], ui1 = x1[(2 * l + 1) * LQ];
    float pr = ur0 * ur1 - ui0 * ui1;
    float pi = ur0 * ui1 + ui0 * ur1;
    for (int d = 1; d < 64; d <<= 1) {
        float qr = __shfl_up(pr, d, 64);
        float qi = __shfl_up(pi, d, 64);
        if (l >= d) {
            float nr = qr * pr - qi * pi;
            float ni = qr * pi + qi * pr;
            pr = nr; pi = ni;
        }
    }
    float er = __shfl_up(pr, 1, 64);
    float ei = __shfl_up(pi, 1, 64);
    if (l == 0) { er = 1.f; ei = 0.f; }
    float e1r = er * ur0 - ei * ui0;
    float e1i = er * ui0 + ei * ur0;

    const float* yrp = x + (size_t)(b * 4 + 2) * LL;
    const float* yip = yrp + LL;
    float4* seed4 = (float4*)ws;

    for (int k = 0; k < 4; ++k) {
        int i = rq * 16 + w * 4 + k;
        float cxr = __shfl((i & 1) ? e1r : er, i >> 1, 64);
        float cxi = __shfl((i & 1) ? e1i : ei, i >> 1, 64);
        const float* yr = yrp + (size_t)i * LQ;
        const float* yi = yip + (size_t)i * LQ;
        float vr0 = yr[2 * l],     vi0 = yi[2 * l];
        float vr1 = yr[2 * l + 1], vi1 = yi[2 * l + 1];
        float sr = vr0 * vr1 - vi0 * vi1;
        float si = vr0 * vi1 + vi0 * vr1;
        for (int d = 1; d < 64; d <<= 1) {
            float qr = __shfl_up(sr, d, 64);
            float qi = __shfl_up(si, d, 64);
            if (l >= d) {
                float nr = qr * sr - qi * si;
                float ni = qr * si + qi * sr;
                sr = nr; si = ni;
            }
        }
        float gr = __shfl_up(sr, 1, 64);
        float gi = __shfl_up(si, 1, 64);
        if (l == 0) { gr = 1.f; gi = 0.f; }
        float s0r = cxr * gr - cxi * gi;
        float s0i = cxr * gi + cxi * gr;
        float s1r = s0r * vr0 - s0i * vi0;
        float s1i = s0r * vi0 + s0i * vr0;
        seed4[((size_t)b * LL + (size_t)i * LQ) / 2 + l] =
            make_float4(s0r, -s0i, s1r, -s1i);
    }
}

// ---------------------------------------------------------------------------
__global__ __launch_bounds__(256, 4)
void k_main(const float* __restrict__ x,
            const float* __restrict__ c2, const float* __restrict__ fw2,
            const float* __restrict__ bw2, const float* __restrict__ b1,
            const float* __restrict__ b2,
            const float* __restrict__ ro, const float* __restrict__ rob,
            const float* __restrict__ ws, float* __restrict__ out) {
    __shared__ unsigned s_f1r[NPTS * FSTR];  // bf16 pairs, h-major: 12960 B
    __shared__ unsigned s_f1i[NPTS * FSTR];  // 12960 B
    __shared__ f2 s_ux[LKN];                 // 4232 B
    __shared__ f2 s_uy[LKN];                 // 4232 B
    __shared__ float s_pc[PCN];              // 1936 B
    __shared__ f2 s_sd[SDN];                 // 3200 B  (total 39520 -> 4 blk/CU)
    int tid = threadIdx.x;
    int b = blockIdx.z, i0 = blockIdx.y * TILE, j0 = blockIdx.x * TILE;
    const float* x0 = x + (size_t)b * 4 * LL;
    const float* x1 = x0 + LL;
    const float* x2 = x0 + 2 * LL;
    const float* x3 = x0 + 3 * LL;
    const float2* seed = (const float2*)ws + (size_t)b * LL;
    const float2* W1 = (const float2*)ws + WS_W1;

    // uniform zero-bias fast-path flags (exact: scale==1.0 when bias==0)
    bool z1 = true;
#pragma unroll
    for (int h = 0; h < H1; ++h) z1 = z1 && (b1[h] == 0.f);
    bool z2 = true;
#pragma unroll
    for (int o = 0; o < O2; ++o) z2 = z2 && (b2[o] == 0.f);

    // ---- Phase A: stage links (23x23, origin -3) + seed (20x20, origin -2) ----
    for (int p = tid; p < LKN; p += 256) {
        int ri = p / LKR, rj = p - ri * LKR;
        int gi = wrapi(i0 - 3 + ri), gj = wrapi(j0 - 3 + rj);
        int idx = gi * LQ + gj;
        s_ux[p] = (f2){x0[idx], x1[idx]};
        s_uy[p] = (f2){x2[idx], x3[idx]};
    }
    for (int p = tid; p < SDN; p += 256) {
        int ri = p / SDR, rj = p - ri * SDR;
        int gi = wrapi(i0 - 2 + ri), gj = wrapi(j0 - 2 + rj);
        float2 s = seed[gi * LQ + gj];
        s_sd[p] = (f2){s.x, s.y};
    }
    __syncthreads();

    // ---- Phase B: pc on 22x22 (origin -3) via complex plaquette product ----
    for (int p = tid; p < PCN; p += 256) {
        int ri = p / PCR, rj = p - ri * PCR;
        int lb = ri * LKR + rj;
        f2 u1 = s_ux[lb];
        f2 u2 = s_uy[lb + LKR];
        f2 u3 = s_ux[lb + 1];
        f2 u4 = s_uy[lb];
        float ar = u1.x * u2.x - u1.y * u2.y, ai = u1.x * u2.y + u1.y * u2.x;
        float br = ar * u3.x + ai * u3.y,     bi = -ar * u3.y + ai * u3.x;
        float zr = br * u4.x + bi * u4.y,     zi = -br * u4.y + bi * u4.x;
        s_pc[p] = zr * __frsqrt_rn(fmaf(zr, zr, zi * zi) + 1e-30f);
    }
    __syncthreads();

    // ---- Phase C: layer1 (+modrelu) on 18x18 -> split bf16 h-major planes ----
#pragma unroll
    for (int pass = 0; pass < 2; ++pass) {
        int p = tid + pass * 256;
        if (pass == 1 && p >= NPTS) break;
        int ri = p / REG, rj = p - ri * REG;
        int sc = (ri + 1) * SDR + (rj + 1);
        int lb = (ri + 2) * LKR + (rj + 2);
        int cb = (ri + 2) * PCR + (rj + 2);

        f2 t[5]; float tc[5], tv[5];
        {
            f2 SC = s_sd[sc], SXP = s_sd[sc + SDR], SXM = s_sd[sc - SDR];
            f2 SYP = s_sd[sc + 1], SYM = s_sd[sc - 1];
            f2 lx = s_ux[lb], ly = s_uy[lb];
            f2 mx = s_ux[lb - LKR], my = s_uy[lb - 1];
            t[0] = SC;
            t[1] = (f2){lx.x * SXP.x - lx.y * SXP.y, lx.x * SXP.y + lx.y * SXP.x};
            t[2] = (f2){mx.x * SXM.x + mx.y * SXM.y, mx.x * SXM.y - mx.y * SXM.x};
            t[3] = (f2){ly.x * SYP.x - ly.y * SYP.y, ly.x * SYP.y + ly.y * SYP.x};
            t[4] = (f2){my.x * SYM.x + my.y * SYM.y, my.x * SYM.y - my.y * SYM.x};
            // 13-point pc diamond (dedup of 5 overlapping 5-point stencils)
            float p00 = s_pc[cb];
            float pP0 = s_pc[cb + PCR],     pM0 = s_pc[cb - PCR];
            float p0P = s_pc[cb + 1],       p0M = s_pc[cb - 1];
            float pP20 = s_pc[cb + 2*PCR],  pM20 = s_pc[cb - 2*PCR];
            float p0P2 = s_pc[cb + 2],      p0M2 = s_pc[cb - 2];
            float pPP = s_pc[cb + PCR + 1], pPM = s_pc[cb + PCR - 1];
            float pMP = s_pc[cb - PCR + 1], pMM = s_pc[cb - PCR - 1];
            tc[0] = p00; tc[1] = pP0; tc[2] = pM0; tc[3] = p0P; tc[4] = p0M;
            tv[0] = (p00 + pP0 + pM0 + p0P + p0M) * 0.2f;
            tv[1] = (pP0 + pP20 + p00 + pPP + pPM) * 0.2f;
            tv[2] = (pM0 + p00 + pM20 + pMP + pMM) * 0.2f;
            tv[3] = (p0P + pPP + pMP + p0P2 + p00) * 0.2f;
            tv[4] = (p0M + pPM + pMM + p00 + p0M2) * 0.2f;
        }

        f2 accr[8], acci[8];
#pragma unroll
        for (int op = 0; op < 8; ++op) { accr[op] = (f2){0.f, 0.f}; acci[op] = (f2){0.f, 0.f}; }
#pragma unroll
        for (int q = 0; q < 5; ++q) {
            f2 tcv = (f2){tc[q], tc[q]}, tvv = (f2){tv[q], tv[q]};
            f2 trv = (f2){t[q].x, t[q].x}, tiv = (f2){t[q].y, t[q].y};
            const float2* Wq = W1 + q * 24;
#pragma unroll
            for (int op = 0; op < 8; ++op) {
                float2 w0 = Wq[op], w1 = Wq[8 + op], w2 = Wq[16 + op];
                f2 mp = (f2){w0.x, w0.y};
                mp += (f2){w1.x, w1.y} * tcv;
                mp += (f2){w2.x, w2.y} * tvv;
                accr[op] += mp * trv;
                acci[op] += mp * tiv;
            }
        }
        if (!z1) {
#pragma unroll
            for (int op = 0; op < 8; ++op) {
                f2 q2 = accr[op] * accr[op] + acci[op] * acci[op] + (f2){1e-12f, 1e-12f};
                float s0 = fmaxf(fmaf(b1[2 * op],     __frsqrt_rn(q2.x), 1.f), 0.f);
                float s1 = fmaxf(fmaf(b1[2 * op + 1], __frsqrt_rn(q2.y), 1.f), 0.f);
                f2 sv = (f2){s0, s1};
                accr[op] *= sv; acci[op] *= sv;
            }
        }
        // pack: plane dword op holds (h=2op low16, h=2op+1 high16), v_perm trunc
        unsigned* fr_ = &s_f1r[p * FSTR];
        unsigned* fi_ = &s_f1i[p * FSTR];
#pragma unroll
        for (int d = 0; d < 4; ++d) {
            unsigned r0 = pack_bf(accr[2*d].y,   accr[2*d].x);
            unsigned r1 = pack_bf(accr[2*d+1].y, accr[2*d+1].x);
            unsigned q0 = pack_bf(acci[2*d].y,   acci[2*d].x);
            unsigned q1 = pack_bf(acci[2*d+1].y, acci[2*d+1].x);
            *(uint2*)&fr_[2*d] = make_uint2(r0, r1);
            *(uint2*)&fi_[2*d] = make_uint2(q0, q1);
        }
    }
    __syncthreads();

    // ---- Phase D: layer2 via tap-paired MFMA + readout ----
    // pair p: K 0-15 = tapLo (A rows 0-7), K 16-31 = tapHi (A rows 8-15)
    // pairs: (center, fwd_x), (bwd_x, fwd_y), (bwd_y, -)
    int lane = tid & 63, w = tid >> 6;
    int quad = lane >> 4, nIdx = lane & 15;
    int half = quad >> 1;            // 0: lowK tap, 1: highK tap
    int koff = (quad & 1) * 4;       // dword offset within a plane's 8

    const float* wLo[3] = {c2, bw2, bw2 + O2 * H1};
    const float* wHi[3] = {fw2, fw2 + O2 * H1, (const float*)0};
    bf8 afr[3];
#pragma unroll
    for (int pq = 0; pq < 3; ++pq) {
        bf8 z = {0, 0, 0, 0, 0, 0, 0, 0};
        const float* wsrc = half ? wHi[pq] : wLo[pq];
        int row = half ? (nIdx - 8) : nIdx;
        bool valid = half ? (nIdx >= 8 && wsrc != 0) : (nIdx < 8);
        if (valid) {
            const float* wp = wsrc + row * H1 + (quad & 1) * 8;
            float4 wa = *(const float4*)wp;
            float4 wb = *(const float4*)(wp + 4);
            uint4 u;
            u.x = pack_bf(wa.y, wa.x);
            u.y = pack_bf(wa.w, wa.z);
            u.z = pack_bf(wb.y, wb.x);
            u.w = pack_bf(wb.w, wb.z);
            __builtin_memcpy(&z, &u, 16);
        }
        afr[pq] = z;
    }
    float4 ro_lo = *(const float4*)ro;
    float4 ro_hi = *(const float4*)(ro + 4);
    float4 b2_lo = *(const float4*)b2;
    float4 b2_hi = *(const float4*)(b2 + 4);
    float4 zf4 = make_float4(0.f, 0.f, 0.f, 0.f);
    float4 rv = (quad == 0) ? ro_lo : ((quad == 1) ? ro_hi : zf4);
    float4 bv = (quad == 0) ? b2_lo : ((quad == 1) ? b2_hi : zf4);
    float rob0 = rob[0];

    for (int g = 0; g < 4; ++g) {
        int row = w * 4 + g;
        int posc = (row + 1) * REG + (nIdx + 1);
        int lb2 = (row + 3) * LKR + (nIdx + 3);
        f2 lx = s_ux[lb2], ly = s_uy[lb2];
        f2 mx = s_ux[lb2 - LKR], my = s_uy[lb2 - 1];

        // per-pair per-lane link rotation (half selects lo/hi tap)
        float Lr[3], Li[3];
        Lr[0] = half ? lx.x : 1.f;   Li[0] = half ? lx.y : 0.f;
        Lr[1] = half ? ly.x : mx.x;  Li[1] = half ? ly.y : -mx.y;
        Lr[2] = half ? 0.f : my.x;   Li[2] = half ? 0.f : -my.y;
        // per-pair per-lane B tap offset
        int dpl[3];
        dpl[0] = half ? REG : 0;
        dpl[1] = half ? 1 : -REG;
        dpl[2] = -1;

        f4 a2r = {0.f, 0.f, 0.f, 0.f}, a2i = {0.f, 0.f, 0.f, 0.f};
#pragma unroll
        for (int pq = 0; pq < 3; ++pq) {
            int base = (posc + dpl[pq]) * FSTR + koff;
            uint2 rlo = *(const uint2*)&s_f1r[base];
            uint2 rhi = *(const uint2*)&s_f1r[base + 2];
            uint2 ilo = *(const uint2*)&s_f1i[base];
            uint2 ihi = *(const uint2*)&s_f1i[base + 2];
            bf8 br, bi;
            uint4 ur = {rlo.x, rlo.y, rhi.x, rhi.y};
            uint4 ui = {ilo.x, ilo.y, ihi.x, ihi.y};
            __builtin_memcpy(&br, &ur, 16);
            __builtin_memcpy(&bi, &ui, 16);
            f4 zc = {0.f, 0.f, 0.f, 0.f};
            f4 sr = __builtin_amdgcn_mfma_f32_16x16x32_bf16(afr[pq], br, zc, 0, 0, 0);
            f4 si = __builtin_amdgcn_mfma_f32_16x16x32_bf16(afr[pq], bi, zc, 0, 0, 0);
            a2r += Lr[pq] * sr - Li[pq] * si;
            a2i += Lr[pq] * si + Li[pq] * sr;
        }

        // fold highK-half rows (8-15, in quads 2/3) into lowK rows (quads 0/1)
#pragma unroll
        for (int c = 0; c < 4; ++c) {
            a2r[c] += __shfl_xor(a2r[c], 32, 64);
            a2i[c] += __shfl_xor(a2i[c], 32, 64);
        }

        f4 q4 = a2r * a2r + a2i * a2i;
        float res;
        if (z2) {
            res = rv.x * q4.x + rv.y * q4.y + rv.z * q4.z + rv.w * q4.w;
        } else {
            float bvv[4] = {bv.x, bv.y, bv.z, bv.w};
            float rvv[4] = {rv.x, rv.y, rv.z, rv.w};
            res = 0.f;
#pragma unroll
            for (int r = 0; r < 4; ++r) {
                float qq = q4[r];
                float s = fmaxf(fmaf(bvv[r], __frsqrt_rn(qq + 1e-12f), 1.f), 0.f);
                res = fmaf(rvv[r], s * s * qq, res);
            }
        }
        res += __shfl_xor(res, 16, 64);
        if (quad == 0)
            out[(size_t)b * LL + (size_t)(i0 + row) * LQ + (j0 + nIdx)] = res + rob0;
    }
}

// ---------------------------------------------------------------------------
extern "C" void kernel_launch(void* const* d_in, const int* in_sizes, int n_in,
                              void* d_out, int out_size, void* d_ws, size_t ws_size,
                              hipStream_t stream) {
    const float* x   = (const float*)d_in[0];
    const float* c1  = (const float*)d_in[1];
    const float* fw1 = (const float*)d_in[2];
    const float* bw1 = (const float*)d_in[3];
    const float* b1  = (const float*)d_in[4];
    const float* c2  = (const float*)d_in[5];
    const float* fw2 = (const float*)d_in[6];
    const float* bw2 = (const float*)d_in[7];
    const float* b2  = (const float*)d_in[8];
    const float* ro  = (const float*)d_in[9];
    const float* rob = (const float*)d_in[10];
    float* out = (float*)d_out;
    float* ws  = (float*)d_ws;

    k_scan<<<BQ * 8 + 1, 256, 0, stream>>>(x, c1, fw1, bw1, ws);
    dim3 grid(LQ / TILE, LQ / TILE, BQ);
    k_main<<<grid, 256, 0, stream>>>(x, c2, fw2, bw2, b1, b2,
                                     ro, rob, ws, out);
}